// Round 9
// baseline (1324.385 us; speedup 1.0000x reference)
//
#include <hip/hip_runtime.h>
#include <hip/hip_bf16.h>

#define A_N 152
#define V_N 26
#define M_N 3952          // A_N*V_N, = 247*16 exactly
#define M_PAD 3968        // 62*64
#define CIN 512
#define FDIM 256
#define HW_SZ 16384
#define P_TOT 131072.0f   // 8*16384
#define TEMP_INV 14.285714285714286f
#define NGRP 2048         // 8 images * 256 groups of 64 px
#define LCAP 64           // max samples per pixel-group

typedef __attribute__((ext_vector_type(8))) short bf16x8;
typedef __attribute__((ext_vector_type(4))) float f32x4;

static __device__ __forceinline__ short f2bf(float x){
  union { float f; unsigned u; } v; v.f = x;
  unsigned r = (v.u + 0x7FFFu + ((v.u >> 16) & 1u)) >> 16;
  return (short)r;
}

// Load an MFMA 16x16x32 A/B fragment from a row-major [rows][ld] bf16 matrix.
static __device__ __forceinline__ bf16x8 ldfrag(const short* __restrict__ base, int ld,
                                                int row, int k, int lane){
  return *(const bf16x8*)(base + (size_t)(row + (lane & 15)) * ld + k + ((lane >> 4) << 3));
}

// convert+store 4 px of channel tid into the XOR-swizzled [px][c] LDS tile.
// float4 BY VALUE (R1 lesson: address-taken float4 arrays go to scratch).
static __device__ __forceinline__ void cvt4(short* __restrict__ lds, float4 v,
                                            int px, int tid){
  lds[(px+0)*512 + (tid ^ (((px+0)&7)<<3))] = f2bf(v.x);
  lds[(px+1)*512 + (tid ^ (((px+1)&7)<<3))] = f2bf(v.y);
  lds[(px+2)*512 + (tid ^ (((px+2)&7)<<3))] = f2bf(v.z);
  lds[(px+3)*512 + (tid ^ (((px+3)&7)<<3))] = f2bf(v.w);
}

// ---------------------------------------------------------------- weights cast (all 4 at once)
__global__ void castw_kernel(const float* __restrict__ a0, short* __restrict__ o0,
                             const float* __restrict__ a1, short* __restrict__ o1,
                             const float* __restrict__ a2, short* __restrict__ o2,
                             const float* __restrict__ a3, short* __restrict__ o3){
  const float* a; short* o; int n;
  switch (blockIdx.y){
    case 0: a = a0; o = o0; n = CIN*CIN; break;
    case 1: a = a1; o = o1; n = CIN*CIN; break;
    case 2: a = a2; o = o2; n = FDIM*CIN; break;
    default: a = a3; o = o3; n = FDIM*CIN; break;
  }
  int i = blockIdx.x * 256 + threadIdx.x;
  if (i < n) o[i] = f2bf(a[i]);
}

// ---------------------------------------------------------------- sample -> pixel-group lists
// Entry packs (px<<16)|m so the stats gather needs no dependent si load.
__global__ __launch_bounds__(64) void build_lists_kernel(
    const int* __restrict__ sb, const int* __restrict__ si,
    int* __restrict__ counts, int* __restrict__ lists){
  int m = blockIdx.x * 64 + threadIdx.x;
  if (m >= M_N) return;
  int a = m % A_N, v = m / A_N;
  int pix = si[a * V_N + v];
  int g = sb[a] * 256 + (pix >> 6);
  int slot = atomicAdd(&counts[g], 1);
  if (slot < LCAP) lists[g * LCAP + slot] = m | ((pix & 63) << 16);
}

// ---------------------------------------------------------------- BN statistics (+ fused gather)
// sums[d] = sum_p h, sums[512+d] = sum_p h^2, h = W1 . x (b1 cancels in BN).
// EXACT R0 structure (best measured 405us): grid (512,2), 4 tiles/block, 64KB LDS,
// c=tid staging in 4-load groups, (px&7)<<3 swizzle, acc[4][4] single pass.
// 8 rounds of single-variable edits (schedule x2, nt, coalescing x2, acc-split,
// W1-LDS) were all null or regressions -> this round ships R0 and MEASURES phase
// attribution via the diag kernels below instead of theorizing it.
__global__ __launch_bounds__(512) void stats_kernel(
    const float* __restrict__ xS, const float* __restrict__ xT,
    const short* __restrict__ w1S, const short* __restrict__ w1T,
    float* __restrict__ stats,
    const int* __restrict__ counts, const int* __restrict__ lists,
    short* __restrict__ xsS, short* __restrict__ xsT){
  __shared__ short lds[64 * 512];        // 64 px x 512 c, c XOR-swizzled by ((px&7)<<3)
  const int t = blockIdx.y;
  const float* __restrict__ x = t ? xT : xS;
  const short* __restrict__ w1 = t ? w1T : w1S;
  float* sums = stats + t * 1024;
  short* __restrict__ xs = t ? xsT : xsS;

  const int tid  = threadIdx.x;
  const int lane = tid & 63;
  const int wave = tid >> 6;
  const int d0   = wave * 64;

  float rs[4] = {0.f,0.f,0.f,0.f};
  float rq[4] = {0.f,0.f,0.f,0.f};

  for (int it = 0; it < 4; ++it){
    const int g   = blockIdx.x + it * 512;   // 0..2047 pixel-groups of 64
    const int n   = g >> 8;
    const int hw0 = (g & 255) << 6;
    const float* src = x + ((size_t)(n * CIN + tid)) * HW_SZ + hw0;  // c = tid

    int cnt = counts[g];                 // hoisted: latency hides under staging
    if (cnt > LCAP) cnt = LCAP;

    // stage 64 px x 512 c as bf16 in 4 chunks of 16 px (4 loads in flight/group)
    #pragma unroll
    for (int ch = 0; ch < 4; ++ch){
      float4 v0 = *(const float4*)(src + ch * 16 +  0);
      float4 v1 = *(const float4*)(src + ch * 16 +  4);
      float4 v2 = *(const float4*)(src + ch * 16 +  8);
      float4 v3 = *(const float4*)(src + ch * 16 + 12);
      cvt4(lds, v0, ch * 16 +  0, tid);
      cvt4(lds, v1, ch * 16 +  4, tid);
      cvt4(lds, v2, ch * 16 +  8, tid);
      cvt4(lds, v3, ch * 16 + 12, tid);
    }
    __syncthreads();

    // fused gather: copy sampled pixel columns (bf16) out of LDS (px packed in list)
    for (int s = 0; s < cnt; ++s){
      int e = lists[g * LCAP + s];
      int m = e & 0xFFFF, px = e >> 16;
      xs[(size_t)m * CIN + tid] = lds[px * 512 + (tid ^ ((px & 7) << 3))];
    }

    f32x4 acc[4][4] = {};                  // [px-tile][d-tile]
    for (int kk = 0; kk < CIN; kk += 32){
      bf16x8 bfr[4];
      #pragma unroll
      for (int di = 0; di < 4; ++di) bfr[di] = ldfrag(w1, CIN, d0 + di*16, kk, lane);
      #pragma unroll
      for (int pi = 0; pi < 4; ++pi){
        int px = pi*16 + (lane & 15);
        int c  = (kk + ((lane >> 4) << 3)) ^ ((px & 7) << 3);
        bf16x8 af = *(const bf16x8*)(lds + px*512 + c);
        #pragma unroll
        for (int di = 0; di < 4; ++di)
          acc[pi][di] = __builtin_amdgcn_mfma_f32_16x16x32_bf16(af, bfr[di], acc[pi][di], 0, 0, 0);
      }
    }
    #pragma unroll
    for (int di = 0; di < 4; ++di){
      float s = 0.f, q2 = 0.f;
      #pragma unroll
      for (int pi = 0; pi < 4; ++pi)
        #pragma unroll
        for (int r = 0; r < 4; ++r){ float vv = acc[pi][di][r]; s += vv; q2 += vv*vv; }
      rs[di] += s; rq[di] += q2;
    }
    __syncthreads();
  }
  #pragma unroll
  for (int di = 0; di < 4; ++di){
    float s = rs[di], q2 = rq[di];
    s  += __shfl_xor(s, 16, 64);  s  += __shfl_xor(s, 32, 64);
    q2 += __shfl_xor(q2, 16, 64); q2 += __shfl_xor(q2, 32, 64);
    if ((lane & 48) == 0){
      int d = d0 + di*16 + lane;
      atomicAdd(&sums[d], s);
      atomicAdd(&sums[512 + d], q2);
    }
  }
}

// ---------------------------------------------------------------- DIAG: staging+gather only
// Replicates stats' staging phase in isolation (8 its = 2 full x passes, g wraps).
// LDS kept live via gather + keepalive read (rule #17: asm blocks DCE).
__global__ __launch_bounds__(512) void diag_stage_kernel(
    const float* __restrict__ xS, const float* __restrict__ xT,
    const int* __restrict__ counts, const int* __restrict__ lists,
    short* __restrict__ xsd){
  __shared__ short lds[64 * 512];
  const float* __restrict__ x = blockIdx.y ? xT : xS;
  const int tid = threadIdx.x;

  for (int it = 0; it < 8; ++it){
    const int g   = (blockIdx.x + it * 512) & (NGRP - 1);
    const int n   = g >> 8;
    const int hw0 = (g & 255) << 6;
    const float* src = x + ((size_t)(n * CIN + tid)) * HW_SZ + hw0;
    int cnt = counts[g]; if (cnt > LCAP) cnt = LCAP;

    #pragma unroll
    for (int ch = 0; ch < 4; ++ch){
      float4 v0 = *(const float4*)(src + ch * 16 +  0);
      float4 v1 = *(const float4*)(src + ch * 16 +  4);
      float4 v2 = *(const float4*)(src + ch * 16 +  8);
      float4 v3 = *(const float4*)(src + ch * 16 + 12);
      cvt4(lds, v0, ch * 16 +  0, tid);
      cvt4(lds, v1, ch * 16 +  4, tid);
      cvt4(lds, v2, ch * 16 +  8, tid);
      cvt4(lds, v3, ch * 16 + 12, tid);
    }
    __syncthreads();

    for (int s = 0; s < cnt; ++s){
      int e = lists[g * LCAP + s];
      int m = e & 0xFFFF, px = e >> 16;
      xsd[(size_t)m * CIN + tid] = lds[px * 512 + (tid ^ ((px & 7) << 3))];
    }
    short v = lds[(tid * 131) & (64 * 512 - 1)];
    asm volatile("" :: "v"((int)v));
    __syncthreads();
  }
}

// ---------------------------------------------------------------- DIAG: frag-load+MFMA only
// Replicates stats' compute phase in isolation (8 its). LDS uninitialized (values
// irrelevant); accumulators kept alive via asm, nothing stored.
__global__ __launch_bounds__(512) void diag_mfma_kernel(
    const short* __restrict__ w1S, const short* __restrict__ w1T){
  __shared__ short lds[64 * 512];
  const short* __restrict__ w1 = blockIdx.y ? w1T : w1S;
  const int lane = threadIdx.x & 63;
  const int wave = threadIdx.x >> 6;
  const int d0   = wave * 64;

  float rs[4] = {0.f,0.f,0.f,0.f};
  float rq[4] = {0.f,0.f,0.f,0.f};

  for (int it = 0; it < 8; ++it){
    f32x4 acc[4][4] = {};
    for (int kk = 0; kk < CIN; kk += 32){
      bf16x8 bfr[4];
      #pragma unroll
      for (int di = 0; di < 4; ++di) bfr[di] = ldfrag(w1, CIN, d0 + di*16, kk, lane);
      #pragma unroll
      for (int pi = 0; pi < 4; ++pi){
        int px = pi*16 + (lane & 15);
        int c  = (kk + ((lane >> 4) << 3)) ^ ((px & 7) << 3);
        bf16x8 af = *(const bf16x8*)(lds + px*512 + c);
        #pragma unroll
        for (int di = 0; di < 4; ++di)
          acc[pi][di] = __builtin_amdgcn_mfma_f32_16x16x32_bf16(af, bfr[di], acc[pi][di], 0, 0, 0);
      }
    }
    #pragma unroll
    for (int di = 0; di < 4; ++di){
      float s = 0.f, q2 = 0.f;
      #pragma unroll
      for (int pi = 0; pi < 4; ++pi)
        #pragma unroll
        for (int r = 0; r < 4; ++r){ float vv = acc[pi][di][r]; s += vv; q2 += vv*vv; }
      rs[di] += s; rq[di] += q2;
    }
    __syncthreads();
  }
  asm volatile("" :: "v"(rs[0]), "v"(rs[1]), "v"(rs[2]), "v"(rs[3]),
                     "v"(rq[0]), "v"(rq[1]), "v"(rq[2]), "v"(rq[3]));
}

// ---------------------------------------------------------------- conv1 + BN + ReLU at samples
__global__ __launch_bounds__(256) void conv1_kernel(
    const short* __restrict__ xsS, const short* __restrict__ xsT,
    const short* __restrict__ w1S, const short* __restrict__ w1T,
    const float* __restrict__ stats,
    const float* __restrict__ gS, const float* __restrict__ bS,
    const float* __restrict__ gT, const float* __restrict__ bT,
    short* __restrict__ hrS, short* __restrict__ hrT){
  const int t = blockIdx.z;
  const short* xs = t ? xsT : xsS;
  const short* w1 = t ? w1T : w1S;
  const float* sums  = stats + t * 1024;
  const float* gamma = t ? gT : gS;
  const float* beta  = t ? bT : bS;
  short* hr = t ? hrT : hrS;

  const int lane = threadIdx.x & 63;
  const int wave = threadIdx.x >> 6;
  const int m0 = blockIdx.x * 16;
  const int d0 = (blockIdx.y * 4 + wave) * 64;

  f32x4 acc[4] = {};
  for (int kk = 0; kk < CIN; kk += 32){
    bf16x8 a = ldfrag(xs, CIN, m0, kk, lane);
    #pragma unroll
    for (int di = 0; di < 4; ++di){
      bf16x8 b = ldfrag(w1, CIN, d0 + di*16, kk, lane);
      acc[di] = __builtin_amdgcn_mfma_f32_16x16x32_bf16(a, b, acc[di], 0, 0, 0);
    }
  }
  const float invP = 1.f / P_TOT;
  #pragma unroll
  for (int di = 0; di < 4; ++di){
    int d = d0 + di*16 + (lane & 15);
    float mu  = sums[d] * invP;
    float var = sums[512 + d] * invP - mu * mu;
    float sc  = gamma[d] * rsqrtf(var + 1e-5f);
    float sh  = beta[d] - mu * sc;
    #pragma unroll
    for (int r = 0; r < 4; ++r){
      int m = m0 + ((lane >> 4) << 2) + r;
      float v = fmaxf(acc[di][r] * sc + sh, 0.f);
      hr[(size_t)m * CIN + d] = f2bf(v);
    }
  }
}

// ---------------------------------------------------------------- conv2 + bias + L2 normalize
__global__ __launch_bounds__(256) void conv2_kernel(
    const short* __restrict__ hrS, const short* __restrict__ hrT,
    const short* __restrict__ w2S, const short* __restrict__ w2T,
    const float* __restrict__ b2S, const float* __restrict__ b2T,
    short* __restrict__ fS, short* __restrict__ fT){
  __shared__ float ssum[4][16];
  const int t = blockIdx.y;
  const short* hr = t ? hrT : hrS;
  const short* w2 = t ? w2T : w2S;
  const float* b2 = t ? b2T : b2S;
  short* f = t ? fT : fS;

  const int lane = threadIdx.x & 63;
  const int wave = threadIdx.x >> 6;
  const int m0 = blockIdx.x * 16;
  const int e0 = wave * 64;

  f32x4 acc[4] = {};
  for (int kk = 0; kk < CIN; kk += 32){
    bf16x8 a = ldfrag(hr, CIN, m0, kk, lane);
    #pragma unroll
    for (int ei = 0; ei < 4; ++ei){
      bf16x8 b = ldfrag(w2, CIN, e0 + ei*16, kk, lane);
      acc[ei] = __builtin_amdgcn_mfma_f32_16x16x32_bf16(a, b, acc[ei], 0, 0, 0);
    }
  }
  float z[4][4];
  float part[4] = {0.f,0.f,0.f,0.f};
  #pragma unroll
  for (int ei = 0; ei < 4; ++ei){
    int e = e0 + ei*16 + (lane & 15);
    float bb = b2[e];
    #pragma unroll
    for (int r = 0; r < 4; ++r){
      float v = acc[ei][r] + bb;
      z[ei][r] = v;
      part[r] += v * v;
    }
  }
  #pragma unroll
  for (int r = 0; r < 4; ++r){
    float p = part[r];
    p += __shfl_xor(p, 1, 64); p += __shfl_xor(p, 2, 64);
    p += __shfl_xor(p, 4, 64); p += __shfl_xor(p, 8, 64);
    part[r] = p;
  }
  if ((lane & 15) == 0){
    #pragma unroll
    for (int r = 0; r < 4; ++r) ssum[wave][((lane >> 4) << 2) + r] = part[r];
  }
  __syncthreads();
  #pragma unroll
  for (int r = 0; r < 4; ++r){
    int mrow = ((lane >> 4) << 2) + r;
    float tot = ssum[0][mrow] + ssum[1][mrow] + ssum[2][mrow] + ssum[3][mrow];
    float sc = 1.f / fmaxf(sqrtf(tot), 1e-12f);
    #pragma unroll
    for (int ei = 0; ei < 4; ++ei){
      int e = e0 + ei*16 + (lane & 15);
      f[(size_t)(m0 + mrow) * FDIM + e] = f2bf(z[ei][r] * sc);
    }
  }
}

// ---------------------------------------------------------------- logits = fa . fb^T / TEMP
// Also writes LT = logits^T when LT != nullptr: logits(fT,fS) == logits(fS,fT)^T
// exactly, so the second logits dispatch is algebraically redundant. Transpose goes
// through a 17-padded LDS tile so LT rows are written as 64B-coalesced chunks.
__global__ __launch_bounds__(64) void logits_kernel(
    const short* __restrict__ fa, const short* __restrict__ fb,
    float* __restrict__ L, float* __restrict__ LT){
  __shared__ float trl[64 * 17];
  const int lane = threadIdx.x;
  const int m0 = blockIdx.x * 16;
  const int n0 = blockIdx.y * 64;
  f32x4 acc[4] = {};
  for (int kk = 0; kk < FDIM; kk += 32){
    bf16x8 a = ldfrag(fa, FDIM, m0, kk, lane);
    #pragma unroll
    for (int ni = 0; ni < 4; ++ni){
      bf16x8 b = ldfrag(fb, FDIM, n0 + ni*16, kk, lane);
      acc[ni] = __builtin_amdgcn_mfma_f32_16x16x32_bf16(a, b, acc[ni], 0, 0, 0);
    }
  }
  #pragma unroll
  for (int ni = 0; ni < 4; ++ni){
    int colL = ni*16 + (lane & 15);
    #pragma unroll
    for (int r = 0; r < 4; ++r){
      int rowL = ((lane >> 4) << 2) + r;
      float val = acc[ni][r] * TEMP_INV;
      L[(size_t)(m0 + rowL) * M_PAD + (n0 + colL)] = val;
      trl[colL * 17 + rowL] = val;
    }
  }
  if (LT){
    __syncthreads();
    float* dst = LT + (size_t)(n0 + lane) * M_PAD + m0;
    #pragma unroll
    for (int jq = 0; jq < 4; ++jq){
      f32x4 tmp;
      tmp.x = trl[lane*17 + jq*4+0];
      tmp.y = trl[lane*17 + jq*4+1];
      tmp.z = trl[lane*17 + jq*4+2];
      tmp.w = trl[lane*17 + jq*4+3];
      *(f32x4*)(dst + jq*4) = tmp;
    }
  }
}

// ---------------------------------------------------------------- per-row contrastive reduction
__global__ __launch_bounds__(256) void loss_kernel(
    const float* __restrict__ L, const int* __restrict__ labels, float* __restrict__ out){
  __shared__ float row[M_N];
  __shared__ float red[4];
  const int m1 = blockIdx.x;
  const int tid = threadIdx.x;
  const int lab1 = labels[m1 % A_N];
  const float* Lr = L + (size_t)m1 * M_PAD;

  float mx = -3.4e38f;
  for (int j = tid; j < M_N; j += 256){ float v = Lr[j]; row[j] = v; mx = fmaxf(mx, v); }
  #pragma unroll
  for (int s = 1; s < 64; s <<= 1) mx = fmaxf(mx, __shfl_xor(mx, s, 64));
  if ((tid & 63) == 0) red[tid >> 6] = mx;
  __syncthreads();
  mx = fmaxf(fmaxf(red[0], red[1]), fmaxf(red[2], red[3]));
  __syncthreads();

  float negp = 0.f;
  for (int j = tid; j < M_N; j += 256){
    int labj = labels[j % A_N];
    float e = __expf(row[j] - mx);
    negp += (labj != lab1) ? e : 0.f;
  }
  #pragma unroll
  for (int s = 1; s < 64; s <<= 1) negp += __shfl_xor(negp, s, 64);
  if ((tid & 63) == 0) red[tid >> 6] = negp;
  __syncthreads();
  float neg = red[0] + red[1] + red[2] + red[3];
  __syncthreads();

  float ps = 0.f, pc = 0.f;
  for (int j = tid; j < M_N; j += 256){
    int labj = labels[j % A_N];
    if (labj == lab1 && j != m1){
      float l = row[j] - mx;
      ps += l - __logf(__expf(l) + neg);
      pc += 1.f;
    }
  }
  #pragma unroll
  for (int s = 1; s < 64; s <<= 1) ps += __shfl_xor(ps, s, 64);
  #pragma unroll
  for (int s = 1; s < 64; s <<= 1) pc += __shfl_xor(pc, s, 64);
  if ((tid & 63) == 0) red[tid >> 6] = ps;
  __syncthreads();
  ps = red[0] + red[1] + red[2] + red[3];
  __syncthreads();
  if ((tid & 63) == 0) red[tid >> 6] = pc;
  __syncthreads();
  if (tid == 0){
    pc = red[0] + red[1] + red[2] + red[3];
    float mlpp = ps / (pc + 1e-6f);
    atomicAdd(out, -0.5f / (float)M_N * mlpp);
  }
}

// ---------------------------------------------------------------- host launch
extern "C" void kernel_launch(void* const* d_in, const int* in_sizes, int n_in,
                              void* d_out, int out_size, void* d_ws, size_t ws_size,
                              hipStream_t stream){
  const float* xS     = (const float*)d_in[0];
  const float* xT     = (const float*)d_in[1];
  const int*   sb     = (const int*)d_in[2];
  const int*   si     = (const int*)d_in[3];
  const int*   labels = (const int*)d_in[4];
  const float* sW1    = (const float*)d_in[5];
  const float* sGamma = (const float*)d_in[7];
  const float* sBeta  = (const float*)d_in[8];
  const float* sW2    = (const float*)d_in[9];
  const float* sB2    = (const float*)d_in[10];
  const float* tW1    = (const float*)d_in[11];
  const float* tGamma = (const float*)d_in[13];
  const float* tBeta  = (const float*)d_in[14];
  const float* tW2    = (const float*)d_in[15];
  const float* tB2    = (const float*)d_in[16];
  float* out = (float*)d_out;

  char* ws = (char*)d_ws;
  size_t off = 0;
  auto alloc = [&](size_t bytes) -> void* {
    void* p = ws + off;
    off = (off + bytes + 255) & ~(size_t)255;
    return p;
  };
  short* w1bS = (short*)alloc((size_t)CIN * CIN * 2);
  short* w1bT = (short*)alloc((size_t)CIN * CIN * 2);
  short* w2bS = (short*)alloc((size_t)FDIM * CIN * 2);
  short* w2bT = (short*)alloc((size_t)FDIM * CIN * 2);
  float* stats = (float*)alloc(2 * 1024 * 4);
  int* counts = (int*)alloc(NGRP * 4);
  int* lists  = (int*)alloc((size_t)NGRP * LCAP * 4);
  short* xsS = (short*)alloc((size_t)M_N * CIN * 2);
  short* xsT = (short*)alloc((size_t)M_N * CIN * 2);
  short* hrS = (short*)alloc((size_t)M_N * CIN * 2);
  short* hrT = (short*)alloc((size_t)M_N * CIN * 2);
  short* fS  = (short*)alloc((size_t)M_PAD * FDIM * 2);
  short* fT  = (short*)alloc((size_t)M_PAD * FDIM * 2);
  float* L   = (float*)alloc((size_t)M_N * M_PAD * 4);
  float* LT  = (float*)alloc((size_t)M_PAD * M_PAD * 4);
  short* xsd = (short*)alloc((size_t)M_N * CIN * 2);   // diag scratch
  const bool haveLT = (off <= ws_size);   // fall back to two logits passes if tight

  hipMemsetAsync(d_out, 0, sizeof(float), stream);
  hipMemsetAsync(stats, 0, 2 * 1024 * 4, stream);
  hipMemsetAsync(counts, 0, NGRP * 4, stream);
  // zero padded f rows so logits tiles touching them stay finite
  hipMemsetAsync(fS + (size_t)M_N * FDIM, 0, (size_t)(M_PAD - M_N) * FDIM * 2, stream);
  hipMemsetAsync(fT + (size_t)M_N * FDIM, 0, (size_t)(M_PAD - M_N) * FDIM * 2, stream);

  castw_kernel<<<dim3((CIN*CIN + 255) / 256, 4), 256, 0, stream>>>(
      sW1, w1bS, tW1, w1bT, sW2, w2bS, tW2, w2bT);
  build_lists_kernel<<<dim3((M_N + 63) / 64), 64, 0, stream>>>(sb, si, counts, lists);

  stats_kernel<<<dim3(512, 2), 512, 0, stream>>>(xS, xT, w1bS, w1bT, stats,
                                                 counts, lists, xsS, xsT);
  conv1_kernel<<<dim3(247, 2, 2), 256, 0, stream>>>(xsS, xsT, w1bS, w1bT, stats,
                                                    sGamma, sBeta, tGamma, tBeta, hrS, hrT);
  conv2_kernel<<<dim3(247, 2), 256, 0, stream>>>(hrS, hrT, w2bS, w2bT, sB2, tB2, fS, fT);

  if (haveLT){
    logits_kernel<<<dim3(247, 62), 64, 0, stream>>>(fS, fT, L, LT);
    loss_kernel<<<dim3(M_N), 256, 0, stream>>>(L, labels, out);
    loss_kernel<<<dim3(M_N), 256, 0, stream>>>(LT, labels, out);
  } else {
    logits_kernel<<<dim3(247, 62), 64, 0, stream>>>(fS, fT, L, nullptr);
    loss_kernel<<<dim3(M_N), 256, 0, stream>>>(L, labels, out);
    logits_kernel<<<dim3(247, 62), 64, 0, stream>>>(fT, fS, L, nullptr);
    loss_kernel<<<dim3(M_N), 256, 0, stream>>>(L, labels, out);
  }

  // ---- diagnostics (results unused; timed via rocprof + total-time subtraction)
  diag_stage_kernel<<<dim3(512, 2), 512, 0, stream>>>(xS, xT, counts, lists, xsd);
  diag_mfma_kernel<<<dim3(512, 2), 512, 0, stream>>>(w1bS, w1bT);
}

// Round 10
// 634.820 us; speedup vs baseline: 2.0862x; 2.0862x over previous
//
#include <hip/hip_runtime.h>
#include <hip/hip_bf16.h>

#define A_N 152
#define V_N 26
#define M_N 3952          // A_N*V_N, = 247*16 exactly
#define M_PAD 3968        // 62*64
#define CIN 512
#define FDIM 256
#define HW_SZ 16384
#define P_TOT 131072.0f   // 8*16384
#define TEMP_INV 14.285714285714286f
#define NGRP 2048         // 8 images * 256 groups of 64 px
#define LCAP 64           // max samples per pixel-group

typedef __attribute__((ext_vector_type(8))) short bf16x8;
typedef __attribute__((ext_vector_type(4))) float f32x4;

static __device__ __forceinline__ short f2bf(float x){
  union { float f; unsigned u; } v; v.f = x;
  unsigned r = (v.u + 0x7FFFu + ((v.u >> 16) & 1u)) >> 16;
  return (short)r;
}

// Load an MFMA 16x16x32 A/B fragment from a row-major [rows][ld] bf16 matrix.
// NOTE (R9 diag): this pattern touches 16 non-adjacent 64B lines per instruction
// (rows are ld*2 bytes apart) -> 64 TCP line-requests per kk when used 4x, which
// capped the isolated compute phase at 23% MfmaUtil. Use ONLY where the matrix
// can't be pre-packed (xs/hr/f tail reads, which are small).
static __device__ __forceinline__ bf16x8 ldfrag(const short* __restrict__ base, int ld,
                                                int row, int k, int lane){
  return *(const bf16x8*)(base + (size_t)(row + (lane & 15)) * ld + k + ((lane >> 4) << 3));
}

// Fragment-packed load: frag (dtile, ktile) is 64 lanes x 16B CONTIGUOUS (1KB).
// packed[((dtile*16+ktile)*64+lane)*8+j] == W[(dtile*16+(lane&15))*CIN + ktile*32 + (lane>>4)*8 + j]
static __device__ __forceinline__ bf16x8 ldfragP(const short* __restrict__ base,
                                                 int dtile, int ktile, int lane){
  return *(const bf16x8*)(base + ((((size_t)dtile << 4) + ktile) << 9) + (lane << 3));
}

// convert+store 4 px of channel tid into the XOR-swizzled [px][c] LDS tile.
// float4 BY VALUE (R1 lesson: address-taken float4 arrays go to scratch).
static __device__ __forceinline__ void cvt4(short* __restrict__ lds, float4 v,
                                            int px, int tid){
  lds[(px+0)*512 + (tid ^ (((px+0)&7)<<3))] = f2bf(v.x);
  lds[(px+1)*512 + (tid ^ (((px+1)&7)<<3))] = f2bf(v.y);
  lds[(px+2)*512 + (tid ^ (((px+2)&7)<<3))] = f2bf(v.z);
  lds[(px+3)*512 + (tid ^ (((px+3)&7)<<3))] = f2bf(v.w);
}

// ---------------------------------------------------------------- weights cast
// W1 (y=0,1): cast AND repack into MFMA-fragment order (see ldfragP).
// W2 (y=2,3): plain cast (conv2's tail cost is small; untouched this round).
__global__ void castw_kernel(const float* __restrict__ a0, short* __restrict__ o0,
                             const float* __restrict__ a1, short* __restrict__ o1,
                             const float* __restrict__ a2, short* __restrict__ o2,
                             const float* __restrict__ a3, short* __restrict__ o3){
  const float* a; short* o; int n;
  switch (blockIdx.y){
    case 0: a = a0; o = o0; n = CIN*CIN; break;
    case 1: a = a1; o = o1; n = CIN*CIN; break;
    case 2: a = a2; o = o2; n = FDIM*CIN; break;
    default: a = a3; o = o3; n = FDIM*CIN; break;
  }
  int i = blockIdx.x * 256 + threadIdx.x;
  if (i >= n) return;
  if (blockIdx.y < 2){
    int j  = i & 7;
    int ln = (i >> 3) & 63;
    int kt = (i >> 9) & 15;
    int dt = i >> 13;
    int row = dt * 16 + (ln & 15);
    int col = kt * 32 + ((ln >> 4) << 3) + j;
    o[i] = f2bf(a[row * CIN + col]);
  } else {
    o[i] = f2bf(a[i]);
  }
}

// ---------------------------------------------------------------- sample -> pixel-group lists
// Entry packs (px<<16)|m so the stats gather needs no dependent si load.
__global__ __launch_bounds__(64) void build_lists_kernel(
    const int* __restrict__ sb, const int* __restrict__ si,
    int* __restrict__ counts, int* __restrict__ lists){
  int m = blockIdx.x * 64 + threadIdx.x;
  if (m >= M_N) return;
  int a = m % A_N, v = m / A_N;
  int pix = si[a * V_N + v];
  int g = sb[a] * 256 + (pix >> 6);
  int slot = atomicAdd(&counts[g], 1);
  if (slot < LCAP) lists[g * LCAP + slot] = m | ((pix & 63) << 16);
}

// ---------------------------------------------------------------- BN statistics (+ fused gather)
// sums[d] = sum_p h, sums[512+d] = sum_p h^2, h = W1 . x (b1 cancels in BN).
// Skeleton = R0 (best, 405us). R10 change, driven by R9's MEASURED ablation:
//   diag_stage (staging alone, 2 full x passes) ~170us -> staging is nearly free;
//   diag_mfma (frag+MFMA alone, LDS DCE'd, W1 L2-resident: FETCH=4MB) = 470us/8it
//   at 23% MfmaUtil -> the kk-loop's W1 frag loads are the wall: 16 scattered
//   lines/instr x 4 = 64 TCP requests per kk per wave.
// Fix: W1 is fragment-packed at cast time; each frag load is now 64x16B contiguous.
__global__ __launch_bounds__(512) void stats_kernel(
    const float* __restrict__ xS, const float* __restrict__ xT,
    const short* __restrict__ w1S, const short* __restrict__ w1T,
    float* __restrict__ stats,
    const int* __restrict__ counts, const int* __restrict__ lists,
    short* __restrict__ xsS, short* __restrict__ xsT){
  __shared__ short lds[64 * 512];        // 64 px x 512 c, c XOR-swizzled by ((px&7)<<3)
  const int t = blockIdx.y;
  const float* __restrict__ x = t ? xT : xS;
  const short* __restrict__ w1 = t ? w1T : w1S;
  float* sums = stats + t * 1024;
  short* __restrict__ xs = t ? xsT : xsS;

  const int tid  = threadIdx.x;
  const int lane = tid & 63;
  const int wave = tid >> 6;

  float rs[4] = {0.f,0.f,0.f,0.f};
  float rq[4] = {0.f,0.f,0.f,0.f};

  for (int it = 0; it < 4; ++it){
    const int g   = blockIdx.x + it * 512;   // 0..2047 pixel-groups of 64
    const int n   = g >> 8;
    const int hw0 = (g & 255) << 6;
    const float* src = x + ((size_t)(n * CIN + tid)) * HW_SZ + hw0;  // c = tid

    int cnt = counts[g];                 // hoisted: latency hides under staging
    if (cnt > LCAP) cnt = LCAP;

    // stage 64 px x 512 c as bf16 in 4 chunks of 16 px (4 loads in flight/group)
    #pragma unroll
    for (int ch = 0; ch < 4; ++ch){
      float4 v0 = *(const float4*)(src + ch * 16 +  0);
      float4 v1 = *(const float4*)(src + ch * 16 +  4);
      float4 v2 = *(const float4*)(src + ch * 16 +  8);
      float4 v3 = *(const float4*)(src + ch * 16 + 12);
      cvt4(lds, v0, ch * 16 +  0, tid);
      cvt4(lds, v1, ch * 16 +  4, tid);
      cvt4(lds, v2, ch * 16 +  8, tid);
      cvt4(lds, v3, ch * 16 + 12, tid);
    }
    __syncthreads();

    // fused gather: copy sampled pixel columns (bf16) out of LDS (px packed in list)
    for (int s = 0; s < cnt; ++s){
      int e = lists[g * LCAP + s];
      int m = e & 0xFFFF, px = e >> 16;
      xs[(size_t)m * CIN + tid] = lds[px * 512 + (tid ^ ((px & 7) << 3))];
    }

    f32x4 acc[4][4] = {};                  // [px-tile][d-tile]
    for (int kk = 0; kk < CIN; kk += 32){
      const int kt = kk >> 5;
      bf16x8 bfr[4];
      #pragma unroll
      for (int di = 0; di < 4; ++di) bfr[di] = ldfragP(w1, wave * 4 + di, kt, lane);
      #pragma unroll
      for (int pi = 0; pi < 4; ++pi){
        int px = pi*16 + (lane & 15);
        int c  = (kk + ((lane >> 4) << 3)) ^ ((px & 7) << 3);
        bf16x8 af = *(const bf16x8*)(lds + px*512 + c);
        #pragma unroll
        for (int di = 0; di < 4; ++di)
          acc[pi][di] = __builtin_amdgcn_mfma_f32_16x16x32_bf16(af, bfr[di], acc[pi][di], 0, 0, 0);
      }
    }
    #pragma unroll
    for (int di = 0; di < 4; ++di){
      float s = 0.f, q2 = 0.f;
      #pragma unroll
      for (int pi = 0; pi < 4; ++pi)
        #pragma unroll
        for (int r = 0; r < 4; ++r){ float vv = acc[pi][di][r]; s += vv; q2 += vv*vv; }
      rs[di] += s; rq[di] += q2;
    }
    __syncthreads();
  }
  #pragma unroll
  for (int di = 0; di < 4; ++di){
    float s = rs[di], q2 = rq[di];
    s  += __shfl_xor(s, 16, 64);  s  += __shfl_xor(s, 32, 64);
    q2 += __shfl_xor(q2, 16, 64); q2 += __shfl_xor(q2, 32, 64);
    if ((lane & 48) == 0){
      int d = wave * 64 + di*16 + lane;
      atomicAdd(&sums[d], s);
      atomicAdd(&sums[512 + d], q2);
    }
  }
}

// ---------------------------------------------------------------- conv1 + BN + ReLU at samples
// w1 is fragment-packed (same tile-16 geometry as stats) -> ldfragP.
__global__ __launch_bounds__(256) void conv1_kernel(
    const short* __restrict__ xsS, const short* __restrict__ xsT,
    const short* __restrict__ w1S, const short* __restrict__ w1T,
    const float* __restrict__ stats,
    const float* __restrict__ gS, const float* __restrict__ bS,
    const float* __restrict__ gT, const float* __restrict__ bT,
    short* __restrict__ hrS, short* __restrict__ hrT){
  const int t = blockIdx.z;
  const short* xs = t ? xsT : xsS;
  const short* w1 = t ? w1T : w1S;
  const float* sums  = stats + t * 1024;
  const float* gamma = t ? gT : gS;
  const float* beta  = t ? bT : bS;
  short* hr = t ? hrT : hrS;

  const int lane = threadIdx.x & 63;
  const int wave = threadIdx.x >> 6;
  const int m0 = blockIdx.x * 16;
  const int dt0 = (blockIdx.y * 4 + wave) * 4;      // dtile base
  const int d0  = dt0 * 16;

  f32x4 acc[4] = {};
  for (int kk = 0; kk < CIN; kk += 32){
    bf16x8 a = ldfrag(xs, CIN, m0, kk, lane);
    #pragma unroll
    for (int di = 0; di < 4; ++di){
      bf16x8 b = ldfragP(w1, dt0 + di, kk >> 5, lane);
      acc[di] = __builtin_amdgcn_mfma_f32_16x16x32_bf16(a, b, acc[di], 0, 0, 0);
    }
  }
  const float invP = 1.f / P_TOT;
  #pragma unroll
  for (int di = 0; di < 4; ++di){
    int d = d0 + di*16 + (lane & 15);
    float mu  = sums[d] * invP;
    float var = sums[512 + d] * invP - mu * mu;
    float sc  = gamma[d] * rsqrtf(var + 1e-5f);
    float sh  = beta[d] - mu * sc;
    #pragma unroll
    for (int r = 0; r < 4; ++r){
      int m = m0 + ((lane >> 4) << 2) + r;
      float v = fmaxf(acc[di][r] * sc + sh, 0.f);
      hr[(size_t)m * CIN + d] = f2bf(v);
    }
  }
}

// ---------------------------------------------------------------- conv2 + bias + L2 normalize
__global__ __launch_bounds__(256) void conv2_kernel(
    const short* __restrict__ hrS, const short* __restrict__ hrT,
    const short* __restrict__ w2S, const short* __restrict__ w2T,
    const float* __restrict__ b2S, const float* __restrict__ b2T,
    short* __restrict__ fS, short* __restrict__ fT){
  __shared__ float ssum[4][16];
  const int t = blockIdx.y;
  const short* hr = t ? hrT : hrS;
  const short* w2 = t ? w2T : w2S;
  const float* b2 = t ? b2T : b2S;
  short* f = t ? fT : fS;

  const int lane = threadIdx.x & 63;
  const int wave = threadIdx.x >> 6;
  const int m0 = blockIdx.x * 16;
  const int e0 = wave * 64;

  f32x4 acc[4] = {};
  for (int kk = 0; kk < CIN; kk += 32){
    bf16x8 a = ldfrag(hr, CIN, m0, kk, lane);
    #pragma unroll
    for (int ei = 0; ei < 4; ++ei){
      bf16x8 b = ldfrag(w2, CIN, e0 + ei*16, kk, lane);
      acc[ei] = __builtin_amdgcn_mfma_f32_16x16x32_bf16(a, b, acc[ei], 0, 0, 0);
    }
  }
  float z[4][4];
  float part[4] = {0.f,0.f,0.f,0.f};
  #pragma unroll
  for (int ei = 0; ei < 4; ++ei){
    int e = e0 + ei*16 + (lane & 15);
    float bb = b2[e];
    #pragma unroll
    for (int r = 0; r < 4; ++r){
      float v = acc[ei][r] + bb;
      z[ei][r] = v;
      part[r] += v * v;
    }
  }
  #pragma unroll
  for (int r = 0; r < 4; ++r){
    float p = part[r];
    p += __shfl_xor(p, 1, 64); p += __shfl_xor(p, 2, 64);
    p += __shfl_xor(p, 4, 64); p += __shfl_xor(p, 8, 64);
    part[r] = p;
  }
  if ((lane & 15) == 0){
    #pragma unroll
    for (int r = 0; r < 4; ++r) ssum[wave][((lane >> 4) << 2) + r] = part[r];
  }
  __syncthreads();
  #pragma unroll
  for (int r = 0; r < 4; ++r){
    int mrow = ((lane >> 4) << 2) + r;
    float tot = ssum[0][mrow] + ssum[1][mrow] + ssum[2][mrow] + ssum[3][mrow];
    float sc = 1.f / fmaxf(sqrtf(tot), 1e-12f);
    #pragma unroll
    for (int ei = 0; ei < 4; ++ei){
      int e = e0 + ei*16 + (lane & 15);
      f[(size_t)(m0 + mrow) * FDIM + e] = f2bf(z[ei][r] * sc);
    }
  }
}

// ---------------------------------------------------------------- logits = fa . fb^T / TEMP
// Also writes LT = logits^T when LT != nullptr: logits(fT,fS) == logits(fS,fT)^T
// exactly, so the second logits dispatch is algebraically redundant. Transpose goes
// through a 17-padded LDS tile so LT rows are written as 64B-coalesced chunks.
__global__ __launch_bounds__(64) void logits_kernel(
    const short* __restrict__ fa, const short* __restrict__ fb,
    float* __restrict__ L, float* __restrict__ LT){
  __shared__ float trl[64 * 17];
  const int lane = threadIdx.x;
  const int m0 = blockIdx.x * 16;
  const int n0 = blockIdx.y * 64;
  f32x4 acc[4] = {};
  for (int kk = 0; kk < FDIM; kk += 32){
    bf16x8 a = ldfrag(fa, FDIM, m0, kk, lane);
    #pragma unroll
    for (int ni = 0; ni < 4; ++ni){
      bf16x8 b = ldfrag(fb, FDIM, n0 + ni*16, kk, lane);
      acc[ni] = __builtin_amdgcn_mfma_f32_16x16x32_bf16(a, b, acc[ni], 0, 0, 0);
    }
  }
  #pragma unroll
  for (int ni = 0; ni < 4; ++ni){
    int colL = ni*16 + (lane & 15);
    #pragma unroll
    for (int r = 0; r < 4; ++r){
      int rowL = ((lane >> 4) << 2) + r;
      float val = acc[ni][r] * TEMP_INV;
      L[(size_t)(m0 + rowL) * M_PAD + (n0 + colL)] = val;
      trl[colL * 17 + rowL] = val;
    }
  }
  if (LT){
    __syncthreads();
    float* dst = LT + (size_t)(n0 + lane) * M_PAD + m0;
    #pragma unroll
    for (int jq = 0; jq < 4; ++jq){
      f32x4 tmp;
      tmp.x = trl[lane*17 + jq*4+0];
      tmp.y = trl[lane*17 + jq*4+1];
      tmp.z = trl[lane*17 + jq*4+2];
      tmp.w = trl[lane*17 + jq*4+3];
      *(f32x4*)(dst + jq*4) = tmp;
    }
  }
}

// ---------------------------------------------------------------- per-row contrastive reduction
__global__ __launch_bounds__(256) void loss_kernel(
    const float* __restrict__ L, const int* __restrict__ labels, float* __restrict__ out){
  __shared__ float row[M_N];
  __shared__ float red[4];
  const int m1 = blockIdx.x;
  const int tid = threadIdx.x;
  const int lab1 = labels[m1 % A_N];
  const float* Lr = L + (size_t)m1 * M_PAD;

  float mx = -3.4e38f;
  for (int j = tid; j < M_N; j += 256){ float v = Lr[j]; row[j] = v; mx = fmaxf(mx, v); }
  #pragma unroll
  for (int s = 1; s < 64; s <<= 1) mx = fmaxf(mx, __shfl_xor(mx, s, 64));
  if ((tid & 63) == 0) red[tid >> 6] = mx;
  __syncthreads();
  mx = fmaxf(fmaxf(red[0], red[1]), fmaxf(red[2], red[3]));
  __syncthreads();

  float negp = 0.f;
  for (int j = tid; j < M_N; j += 256){
    int labj = labels[j % A_N];
    float e = __expf(row[j] - mx);
    negp += (labj != lab1) ? e : 0.f;
  }
  #pragma unroll
  for (int s = 1; s < 64; s <<= 1) negp += __shfl_xor(negp, s, 64);
  if ((tid & 63) == 0) red[tid >> 6] = negp;
  __syncthreads();
  float neg = red[0] + red[1] + red[2] + red[3];
  __syncthreads();

  float ps = 0.f, pc = 0.f;
  for (int j = tid; j < M_N; j += 256){
    int labj = labels[j % A_N];
    if (labj == lab1 && j != m1){
      float l = row[j] - mx;
      ps += l - __logf(__expf(l) + neg);
      pc += 1.f;
    }
  }
  #pragma unroll
  for (int s = 1; s < 64; s <<= 1) ps += __shfl_xor(ps, s, 64);
  #pragma unroll
  for (int s = 1; s < 64; s <<= 1) pc += __shfl_xor(pc, s, 64);
  if ((tid & 63) == 0) red[tid >> 6] = ps;
  __syncthreads();
  ps = red[0] + red[1] + red[2] + red[3];
  __syncthreads();
  if ((tid & 63) == 0) red[tid >> 6] = pc;
  __syncthreads();
  if (tid == 0){
    pc = red[0] + red[1] + red[2] + red[3];
    float mlpp = ps / (pc + 1e-6f);
    atomicAdd(out, -0.5f / (float)M_N * mlpp);
  }
}

// ---------------------------------------------------------------- host launch
extern "C" void kernel_launch(void* const* d_in, const int* in_sizes, int n_in,
                              void* d_out, int out_size, void* d_ws, size_t ws_size,
                              hipStream_t stream){
  const float* xS     = (const float*)d_in[0];
  const float* xT     = (const float*)d_in[1];
  const int*   sb     = (const int*)d_in[2];
  const int*   si     = (const int*)d_in[3];
  const int*   labels = (const int*)d_in[4];
  const float* sW1    = (const float*)d_in[5];
  const float* sGamma = (const float*)d_in[7];
  const float* sBeta  = (const float*)d_in[8];
  const float* sW2    = (const float*)d_in[9];
  const float* sB2    = (const float*)d_in[10];
  const float* tW1    = (const float*)d_in[11];
  const float* tGamma = (const float*)d_in[13];
  const float* tBeta  = (const float*)d_in[14];
  const float* tW2    = (const float*)d_in[15];
  const float* tB2    = (const float*)d_in[16];
  float* out = (float*)d_out;

  char* ws = (char*)d_ws;
  size_t off = 0;
  auto alloc = [&](size_t bytes) -> void* {
    void* p = ws + off;
    off = (off + bytes + 255) & ~(size_t)255;
    return p;
  };
  short* w1bS = (short*)alloc((size_t)CIN * CIN * 2);
  short* w1bT = (short*)alloc((size_t)CIN * CIN * 2);
  short* w2bS = (short*)alloc((size_t)FDIM * CIN * 2);
  short* w2bT = (short*)alloc((size_t)FDIM * CIN * 2);
  float* stats = (float*)alloc(2 * 1024 * 4);
  int* counts = (int*)alloc(NGRP * 4);
  int* lists  = (int*)alloc((size_t)NGRP * LCAP * 4);
  short* xsS = (short*)alloc((size_t)M_N * CIN * 2);
  short* xsT = (short*)alloc((size_t)M_N * CIN * 2);
  short* hrS = (short*)alloc((size_t)M_N * CIN * 2);
  short* hrT = (short*)alloc((size_t)M_N * CIN * 2);
  short* fS  = (short*)alloc((size_t)M_PAD * FDIM * 2);
  short* fT  = (short*)alloc((size_t)M_PAD * FDIM * 2);
  float* L   = (float*)alloc((size_t)M_N * M_PAD * 4);
  float* LT  = (float*)alloc((size_t)M_PAD * M_PAD * 4);
  const bool haveLT = (off <= ws_size);   // fall back to two logits passes if tight

  hipMemsetAsync(d_out, 0, sizeof(float), stream);
  hipMemsetAsync(stats, 0, 2 * 1024 * 4, stream);
  hipMemsetAsync(counts, 0, NGRP * 4, stream);
  // zero padded f rows so logits tiles touching them stay finite
  hipMemsetAsync(fS + (size_t)M_N * FDIM, 0, (size_t)(M_PAD - M_N) * FDIM * 2, stream);
  hipMemsetAsync(fT + (size_t)M_N * FDIM, 0, (size_t)(M_PAD - M_N) * FDIM * 2, stream);

  castw_kernel<<<dim3((CIN*CIN + 255) / 256, 4), 256, 0, stream>>>(
      sW1, w1bS, tW1, w1bT, sW2, w2bS, tW2, w2bT);
  build_lists_kernel<<<dim3((M_N + 63) / 64), 64, 0, stream>>>(sb, si, counts, lists);

  stats_kernel<<<dim3(512, 2), 512, 0, stream>>>(xS, xT, w1bS, w1bT, stats,
                                                 counts, lists, xsS, xsT);
  conv1_kernel<<<dim3(247, 2, 2), 256, 0, stream>>>(xsS, xsT, w1bS, w1bT, stats,
                                                    sGamma, sBeta, tGamma, tBeta, hrS, hrT);
  conv2_kernel<<<dim3(247, 2), 256, 0, stream>>>(hrS, hrT, w2bS, w2bT, sB2, tB2, fS, fT);

  if (haveLT){
    logits_kernel<<<dim3(247, 62), 64, 0, stream>>>(fS, fT, L, LT);
    loss_kernel<<<dim3(M_N), 256, 0, stream>>>(L, labels, out);
    loss_kernel<<<dim3(M_N), 256, 0, stream>>>(LT, labels, out);
  } else {
    logits_kernel<<<dim3(247, 62), 64, 0, stream>>>(fS, fT, L, nullptr);
    loss_kernel<<<dim3(M_N), 256, 0, stream>>>(L, labels, out);
    logits_kernel<<<dim3(247, 62), 64, 0, stream>>>(fT, fS, L, nullptr);
    loss_kernel<<<dim3(M_N), 256, 0, stream>>>(L, labels, out);
  }
}

// Round 11
// 620.862 us; speedup vs baseline: 2.1331x; 1.0225x over previous
//
#include <hip/hip_runtime.h>
#include <hip/hip_bf16.h>

#define A_N 152
#define V_N 26
#define M_N 3952          // A_N*V_N, = 247*16 exactly
#define M_PAD 3968        // 62*64
#define CIN 512
#define FDIM 256
#define HW_SZ 16384
#define P_TOT 131072.0f   // 8*16384
#define TEMP_INV 14.285714285714286f
#define NGRP 2048         // 8 images * 256 groups of 64 px
#define LCAP 64           // max samples per pixel-group

typedef __attribute__((ext_vector_type(8))) short bf16x8;
typedef __attribute__((ext_vector_type(4))) float f32x4;

static __device__ __forceinline__ short f2bf(float x){
  union { float f; unsigned u; } v; v.f = x;
  unsigned r = (v.u + 0x7FFFu + ((v.u >> 16) & 1u)) >> 16;
  return (short)r;
}

// Load an MFMA 16x16x32 A/B fragment from a row-major [rows][ld] bf16 matrix.
static __device__ __forceinline__ bf16x8 ldfrag(const short* __restrict__ base, int ld,
                                                int row, int k, int lane){
  return *(const bf16x8*)(base + (size_t)(row + (lane & 15)) * ld + k + ((lane >> 4) << 3));
}

// Fragment-packed load: frag (dtile, ktile) is 64 lanes x 16B CONTIGUOUS (1KB).
// packed[((dtile*16+ktile)*64+lane)*8+j] == W[(dtile*16+(lane&15))*CIN + ktile*32 + (lane>>4)*8 + j]
static __device__ __forceinline__ bf16x8 ldfragP(const short* __restrict__ base,
                                                 int dtile, int ktile, int lane){
  return *(const bf16x8*)(base + ((((size_t)dtile << 4) + ktile) << 9) + (lane << 3));
}

// convert+store 4 px of channel tid into the XOR-swizzled [px][c] LDS tile.
// float4 BY VALUE (R1 lesson: address-taken float4 arrays go to scratch).
static __device__ __forceinline__ void cvt4(short* __restrict__ lds, float4 v,
                                            int px, int tid){
  lds[(px+0)*512 + (tid ^ (((px+0)&7)<<3))] = f2bf(v.x);
  lds[(px+1)*512 + (tid ^ (((px+1)&7)<<3))] = f2bf(v.y);
  lds[(px+2)*512 + (tid ^ (((px+2)&7)<<3))] = f2bf(v.z);
  lds[(px+3)*512 + (tid ^ (((px+3)&7)<<3))] = f2bf(v.w);
}

// ---------------------------------------------------------------- weights cast
// W1 (y=0,1): cast AND repack into MFMA-fragment order (see ldfragP).
// W2 (y=2,3): plain cast.
__global__ void castw_kernel(const float* __restrict__ a0, short* __restrict__ o0,
                             const float* __restrict__ a1, short* __restrict__ o1,
                             const float* __restrict__ a2, short* __restrict__ o2,
                             const float* __restrict__ a3, short* __restrict__ o3){
  const float* a; short* o; int n;
  switch (blockIdx.y){
    case 0: a = a0; o = o0; n = CIN*CIN; break;
    case 1: a = a1; o = o1; n = CIN*CIN; break;
    case 2: a = a2; o = o2; n = FDIM*CIN; break;
    default: a = a3; o = o3; n = FDIM*CIN; break;
  }
  int i = blockIdx.x * 256 + threadIdx.x;
  if (i >= n) return;
  if (blockIdx.y < 2){
    int j  = i & 7;
    int ln = (i >> 3) & 63;
    int kt = (i >> 9) & 15;
    int dt = i >> 13;
    int row = dt * 16 + (ln & 15);
    int col = kt * 32 + ((ln >> 4) << 3) + j;
    o[i] = f2bf(a[row * CIN + col]);
  } else {
    o[i] = f2bf(a[i]);
  }
}

// ---------------------------------------------------------------- sample -> pixel-group lists
// Entry packs (px<<16)|m so the stats gather needs no dependent si load.
__global__ __launch_bounds__(64) void build_lists_kernel(
    const int* __restrict__ sb, const int* __restrict__ si,
    int* __restrict__ counts, int* __restrict__ lists){
  int m = blockIdx.x * 64 + threadIdx.x;
  if (m >= M_N) return;
  int a = m % A_N, v = m / A_N;
  int pix = si[a * V_N + v];
  int g = sb[a] * 256 + (pix >> 6);
  int slot = atomicAdd(&counts[g], 1);
  if (slot < LCAP) lists[g * LCAP + slot] = m | ((pix & 63) << 16);
}

// ---------------------------------------------------------------- BN statistics (+ fused gather)
// sums[d] = sum_p h, sums[512+d] = sum_p h^2, h = W1 . x (b1 cancels in BN).
// R11: 128-px tiles, 128KB LDS, 1 block/CU, grid (256,2), 4 tiles/block.
// Rationale (R9 diag + R10 null): staging alone runs at FULL HBM BW (85us/pass);
// the MFMA phase is the wall and is occupancy-insensitive (diag at 2x occupancy,
// same per-work rate) and frag-ADDRESS-insensitive (R10 packed null). The binding
// quantity is frag-load ROUNDS per pixel (latency-serialized per wave). 128-px
// tiles amortize each W1 frag round over 2x pixels -> rounds/px halved.
// acc[8][4]=128 VGPR; __launch_bounds__(512,2) grants 256. Spill canary: WRITE_SIZE
// (real spill = +300MB, R1; ambient writeback ~260MB is invariant, R6/R7).
__global__ __launch_bounds__(512, 2) void stats_kernel(
    const float* __restrict__ xS, const float* __restrict__ xT,
    const short* __restrict__ w1S, const short* __restrict__ w1T,
    float* __restrict__ stats,
    const int* __restrict__ counts, const int* __restrict__ lists,
    short* __restrict__ xsS, short* __restrict__ xsT){
  __shared__ short lds[128 * 512];       // 128 px x 512 c, c XOR-swizzled by ((px&7)<<3)
  const int t = blockIdx.y;
  const float* __restrict__ x = t ? xT : xS;
  const short* __restrict__ w1 = t ? w1T : w1S;
  float* sums = stats + t * 1024;
  short* __restrict__ xs = t ? xsT : xsS;

  const int tid  = threadIdx.x;
  const int lane = tid & 63;
  const int wave = tid >> 6;

  float rs[4] = {0.f,0.f,0.f,0.f};
  float rq[4] = {0.f,0.f,0.f,0.f};

  for (int it = 0; it < 4; ++it){
    const int T   = blockIdx.x + it * 256;   // 0..1023 tiles of 128 px
    const int n   = T >> 7;
    const int hw0 = (T & 127) << 7;
    const float* src = x + ((size_t)(n * CIN + tid)) * HW_SZ + hw0;  // c = tid

    const int g0 = T * 2, g1 = g0 + 1;       // the tile's two 64-px sample groups
    int cnt0 = counts[g0]; if (cnt0 > LCAP) cnt0 = LCAP;
    int cnt1 = counts[g1]; if (cnt1 > LCAP) cnt1 = LCAP;

    // stage 128 px x 512 c as bf16 in 8 chunks of 16 px (4 loads in flight/group)
    #pragma unroll
    for (int ch = 0; ch < 8; ++ch){
      float4 v0 = *(const float4*)(src + ch * 16 +  0);
      float4 v1 = *(const float4*)(src + ch * 16 +  4);
      float4 v2 = *(const float4*)(src + ch * 16 +  8);
      float4 v3 = *(const float4*)(src + ch * 16 + 12);
      cvt4(lds, v0, ch * 16 +  0, tid);
      cvt4(lds, v1, ch * 16 +  4, tid);
      cvt4(lds, v2, ch * 16 +  8, tid);
      cvt4(lds, v3, ch * 16 + 12, tid);
    }
    __syncthreads();

    // fused gather from both sub-groups (px packed in list entry; +64 for group 1)
    for (int s = 0; s < cnt0; ++s){
      int e = lists[g0 * LCAP + s];
      int m = e & 0xFFFF, px = e >> 16;
      xs[(size_t)m * CIN + tid] = lds[px * 512 + (tid ^ ((px & 7) << 3))];
    }
    for (int s = 0; s < cnt1; ++s){
      int e = lists[g1 * LCAP + s];
      int m = e & 0xFFFF, px = (e >> 16) + 64;
      xs[(size_t)m * CIN + tid] = lds[px * 512 + (tid ^ ((px & 7) << 3))];
    }

    f32x4 acc[8][4] = {};                  // [px-tile][d-tile]
    for (int kk = 0; kk < CIN; kk += 32){
      const int kt = kk >> 5;
      bf16x8 bfr[4];
      #pragma unroll
      for (int di = 0; di < 4; ++di) bfr[di] = ldfragP(w1, wave * 4 + di, kt, lane);
      #pragma unroll
      for (int pi = 0; pi < 8; ++pi){
        int px = pi*16 + (lane & 15);
        int c  = (kk + ((lane >> 4) << 3)) ^ ((px & 7) << 3);
        bf16x8 af = *(const bf16x8*)(lds + px*512 + c);
        #pragma unroll
        for (int di = 0; di < 4; ++di)
          acc[pi][di] = __builtin_amdgcn_mfma_f32_16x16x32_bf16(af, bfr[di], acc[pi][di], 0, 0, 0);
      }
    }
    #pragma unroll
    for (int di = 0; di < 4; ++di){
      float s = 0.f, q2 = 0.f;
      #pragma unroll
      for (int pi = 0; pi < 8; ++pi)
        #pragma unroll
        for (int r = 0; r < 4; ++r){ float vv = acc[pi][di][r]; s += vv; q2 += vv*vv; }
      rs[di] += s; rq[di] += q2;
    }
    __syncthreads();
  }
  #pragma unroll
  for (int di = 0; di < 4; ++di){
    float s = rs[di], q2 = rq[di];
    s  += __shfl_xor(s, 16, 64);  s  += __shfl_xor(s, 32, 64);
    q2 += __shfl_xor(q2, 16, 64); q2 += __shfl_xor(q2, 32, 64);
    if ((lane & 48) == 0){
      int d = wave * 64 + di*16 + lane;
      atomicAdd(&sums[d], s);
      atomicAdd(&sums[512 + d], q2);
    }
  }
}

// ---------------------------------------------------------------- conv1 + BN + ReLU at samples
// w1 is fragment-packed (same tile-16 geometry as stats) -> ldfragP.
__global__ __launch_bounds__(256) void conv1_kernel(
    const short* __restrict__ xsS, const short* __restrict__ xsT,
    const short* __restrict__ w1S, const short* __restrict__ w1T,
    const float* __restrict__ stats,
    const float* __restrict__ gS, const float* __restrict__ bS,
    const float* __restrict__ gT, const float* __restrict__ bT,
    short* __restrict__ hrS, short* __restrict__ hrT){
  const int t = blockIdx.z;
  const short* xs = t ? xsT : xsS;
  const short* w1 = t ? w1T : w1S;
  const float* sums  = stats + t * 1024;
  const float* gamma = t ? gT : gS;
  const float* beta  = t ? bT : bS;
  short* hr = t ? hrT : hrS;

  const int lane = threadIdx.x & 63;
  const int wave = threadIdx.x >> 6;
  const int m0 = blockIdx.x * 16;
  const int dt0 = (blockIdx.y * 4 + wave) * 4;      // dtile base
  const int d0  = dt0 * 16;

  f32x4 acc[4] = {};
  for (int kk = 0; kk < CIN; kk += 32){
    bf16x8 a = ldfrag(xs, CIN, m0, kk, lane);
    #pragma unroll
    for (int di = 0; di < 4; ++di){
      bf16x8 b = ldfragP(w1, dt0 + di, kk >> 5, lane);
      acc[di] = __builtin_amdgcn_mfma_f32_16x16x32_bf16(a, b, acc[di], 0, 0, 0);
    }
  }
  const float invP = 1.f / P_TOT;
  #pragma unroll
  for (int di = 0; di < 4; ++di){
    int d = d0 + di*16 + (lane & 15);
    float mu  = sums[d] * invP;
    float var = sums[512 + d] * invP - mu * mu;
    float sc  = gamma[d] * rsqrtf(var + 1e-5f);
    float sh  = beta[d] - mu * sc;
    #pragma unroll
    for (int r = 0; r < 4; ++r){
      int m = m0 + ((lane >> 4) << 2) + r;
      float v = fmaxf(acc[di][r] * sc + sh, 0.f);
      hr[(size_t)m * CIN + d] = f2bf(v);
    }
  }
}

// ---------------------------------------------------------------- conv2 + bias + L2 normalize
__global__ __launch_bounds__(256) void conv2_kernel(
    const short* __restrict__ hrS, const short* __restrict__ hrT,
    const short* __restrict__ w2S, const short* __restrict__ w2T,
    const float* __restrict__ b2S, const float* __restrict__ b2T,
    short* __restrict__ fS, short* __restrict__ fT){
  __shared__ float ssum[4][16];
  const int t = blockIdx.y;
  const short* hr = t ? hrT : hrS;
  const short* w2 = t ? w2T : w2S;
  const float* b2 = t ? b2T : b2S;
  short* f = t ? fT : fS;

  const int lane = threadIdx.x & 63;
  const int wave = threadIdx.x >> 6;
  const int m0 = blockIdx.x * 16;
  const int e0 = wave * 64;

  f32x4 acc[4] = {};
  for (int kk = 0; kk < CIN; kk += 32){
    bf16x8 a = ldfrag(hr, CIN, m0, kk, lane);
    #pragma unroll
    for (int ei = 0; ei < 4; ++ei){
      bf16x8 b = ldfrag(w2, CIN, e0 + ei*16, kk, lane);
      acc[ei] = __builtin_amdgcn_mfma_f32_16x16x32_bf16(a, b, acc[ei], 0, 0, 0);
    }
  }
  float z[4][4];
  float part[4] = {0.f,0.f,0.f,0.f};
  #pragma unroll
  for (int ei = 0; ei < 4; ++ei){
    int e = e0 + ei*16 + (lane & 15);
    float bb = b2[e];
    #pragma unroll
    for (int r = 0; r < 4; ++r){
      float v = acc[ei][r] + bb;
      z[ei][r] = v;
      part[r] += v * v;
    }
  }
  #pragma unroll
  for (int r = 0; r < 4; ++r){
    float p = part[r];
    p += __shfl_xor(p, 1, 64); p += __shfl_xor(p, 2, 64);
    p += __shfl_xor(p, 4, 64); p += __shfl_xor(p, 8, 64);
    part[r] = p;
  }
  if ((lane & 15) == 0){
    #pragma unroll
    for (int r = 0; r < 4; ++r) ssum[wave][((lane >> 4) << 2) + r] = part[r];
  }
  __syncthreads();
  #pragma unroll
  for (int r = 0; r < 4; ++r){
    int mrow = ((lane >> 4) << 2) + r;
    float tot = ssum[0][mrow] + ssum[1][mrow] + ssum[2][mrow] + ssum[3][mrow];
    float sc = 1.f / fmaxf(sqrtf(tot), 1e-12f);
    #pragma unroll
    for (int ei = 0; ei < 4; ++ei){
      int e = e0 + ei*16 + (lane & 15);
      f[(size_t)(m0 + mrow) * FDIM + e] = f2bf(z[ei][r] * sc);
    }
  }
}

// ---------------------------------------------------------------- logits = fa . fb^T / TEMP
// R11: 4-wave blocks computing 64x64 tiles (grid 62x62) — 4x fewer blocks, 4x less
// fb L2 re-read. LT = logits^T written via a 64x65-padded LDS tile with coalesced
// 64B row-chunks (logits(fT,fS) == logits(fS,fT)^T exactly, so the second logits
// dispatch is redundant). L is M_PAD rows (padded fa rows are zero -> rows 3952+
// are zeros, never read by loss).
__global__ __launch_bounds__(256) void logits_kernel(
    const short* __restrict__ fa, const short* __restrict__ fb,
    float* __restrict__ L, float* __restrict__ LT){
  __shared__ float trl[64 * 65];
  const int tid  = threadIdx.x;
  const int lane = tid & 63;
  const int wave = tid >> 6;
  const int m0 = blockIdx.x * 64;
  const int n0 = blockIdx.y * 64;
  f32x4 acc[4] = {};
  for (int kk = 0; kk < FDIM; kk += 32){
    bf16x8 a = ldfrag(fa, FDIM, m0 + wave * 16, kk, lane);
    #pragma unroll
    for (int ni = 0; ni < 4; ++ni){
      bf16x8 b = ldfrag(fb, FDIM, n0 + ni*16, kk, lane);
      acc[ni] = __builtin_amdgcn_mfma_f32_16x16x32_bf16(a, b, acc[ni], 0, 0, 0);
    }
  }
  #pragma unroll
  for (int ni = 0; ni < 4; ++ni){
    int colL = ni*16 + (lane & 15);
    #pragma unroll
    for (int r = 0; r < 4; ++r){
      int rowL = wave*16 + ((lane >> 4) << 2) + r;
      float val = acc[ni][r] * TEMP_INV;
      L[(size_t)(m0 + rowL) * M_PAD + (n0 + colL)] = val;
      trl[colL * 65 + rowL] = val;
    }
  }
  if (LT){
    __syncthreads();
    const int rj = tid >> 2;            // 0..63: n-row within tile
    const int cq = (tid & 3) << 4;      // 0,16,32,48: m-col quad base
    float* dst = LT + (size_t)(n0 + rj) * M_PAD + m0 + cq;
    #pragma unroll
    for (int q = 0; q < 4; ++q){
      f32x4 tmp;
      tmp.x = trl[rj*65 + cq + q*4 + 0];
      tmp.y = trl[rj*65 + cq + q*4 + 1];
      tmp.z = trl[rj*65 + cq + q*4 + 2];
      tmp.w = trl[rj*65 + cq + q*4 + 3];
      *(f32x4*)(dst + q*4) = tmp;
    }
  }
}

// ---------------------------------------------------------------- per-row contrastive reduction
__global__ __launch_bounds__(256) void loss_kernel(
    const float* __restrict__ L, const int* __restrict__ labels, float* __restrict__ out){
  __shared__ float row[M_N];
  __shared__ float red[4];
  const int m1 = blockIdx.x;
  const int tid = threadIdx.x;
  const int lab1 = labels[m1 % A_N];
  const float* Lr = L + (size_t)m1 * M_PAD;

  float mx = -3.4e38f;
  for (int j = tid; j < M_N; j += 256){ float v = Lr[j]; row[j] = v; mx = fmaxf(mx, v); }
  #pragma unroll
  for (int s = 1; s < 64; s <<= 1) mx = fmaxf(mx, __shfl_xor(mx, s, 64));
  if ((tid & 63) == 0) red[tid >> 6] = mx;
  __syncthreads();
  mx = fmaxf(fmaxf(red[0], red[1]), fmaxf(red[2], red[3]));
  __syncthreads();

  float negp = 0.f;
  for (int j = tid; j < M_N; j += 256){
    int labj = labels[j % A_N];
    float e = __expf(row[j] - mx);
    negp += (labj != lab1) ? e : 0.f;
  }
  #pragma unroll
  for (int s = 1; s < 64; s <<= 1) negp += __shfl_xor(negp, s, 64);
  if ((tid & 63) == 0) red[tid >> 6] = negp;
  __syncthreads();
  float neg = red[0] + red[1] + red[2] + red[3];
  __syncthreads();

  float ps = 0.f, pc = 0.f;
  for (int j = tid; j < M_N; j += 256){
    int labj = labels[j % A_N];
    if (labj == lab1 && j != m1){
      float l = row[j] - mx;
      ps += l - __logf(__expf(l) + neg);
      pc += 1.f;
    }
  }
  #pragma unroll
  for (int s = 1; s < 64; s <<= 1) ps += __shfl_xor(ps, s, 64);
  #pragma unroll
  for (int s = 1; s < 64; s <<= 1) pc += __shfl_xor(pc, s, 64);
  if ((tid & 63) == 0) red[tid >> 6] = ps;
  __syncthreads();
  ps = red[0] + red[1] + red[2] + red[3];
  __syncthreads();
  if ((tid & 63) == 0) red[tid >> 6] = pc;
  __syncthreads();
  if (tid == 0){
    pc = red[0] + red[1] + red[2] + red[3];
    float mlpp = ps / (pc + 1e-6f);
    atomicAdd(out, -0.5f / (float)M_N * mlpp);
  }
}

// ---------------------------------------------------------------- host launch
extern "C" void kernel_launch(void* const* d_in, const int* in_sizes, int n_in,
                              void* d_out, int out_size, void* d_ws, size_t ws_size,
                              hipStream_t stream){
  const float* xS     = (const float*)d_in[0];
  const float* xT     = (const float*)d_in[1];
  const int*   sb     = (const int*)d_in[2];
  const int*   si     = (const int*)d_in[3];
  const int*   labels = (const int*)d_in[4];
  const float* sW1    = (const float*)d_in[5];
  const float* sGamma = (const float*)d_in[7];
  const float* sBeta  = (const float*)d_in[8];
  const float* sW2    = (const float*)d_in[9];
  const float* sB2    = (const float*)d_in[10];
  const float* tW1    = (const float*)d_in[11];
  const float* tGamma = (const float*)d_in[13];
  const float* tBeta  = (const float*)d_in[14];
  const float* tW2    = (const float*)d_in[15];
  const float* tB2    = (const float*)d_in[16];
  float* out = (float*)d_out;

  char* ws = (char*)d_ws;
  size_t off = 0;
  auto alloc = [&](size_t bytes) -> void* {
    void* p = ws + off;
    off = (off + bytes + 255) & ~(size_t)255;
    return p;
  };
  short* w1bS = (short*)alloc((size_t)CIN * CIN * 2);
  short* w1bT = (short*)alloc((size_t)CIN * CIN * 2);
  short* w2bS = (short*)alloc((size_t)FDIM * CIN * 2);
  short* w2bT = (short*)alloc((size_t)FDIM * CIN * 2);
  float* stats = (float*)alloc(2 * 1024 * 4);
  int* counts = (int*)alloc(NGRP * 4);
  int* lists  = (int*)alloc((size_t)NGRP * LCAP * 4);
  short* xsS = (short*)alloc((size_t)M_N * CIN * 2);
  short* xsT = (short*)alloc((size_t)M_N * CIN * 2);
  short* hrS = (short*)alloc((size_t)M_N * CIN * 2);
  short* hrT = (short*)alloc((size_t)M_N * CIN * 2);
  short* fS  = (short*)alloc((size_t)M_PAD * FDIM * 2);
  short* fT  = (short*)alloc((size_t)M_PAD * FDIM * 2);
  float* L   = (float*)alloc((size_t)M_PAD * M_PAD * 4);
  float* LT  = (float*)alloc((size_t)M_PAD * M_PAD * 4);
  const bool haveLT = (off <= ws_size);   // fall back to two logits passes if tight

  hipMemsetAsync(d_out, 0, sizeof(float), stream);
  hipMemsetAsync(stats, 0, 2 * 1024 * 4, stream);
  hipMemsetAsync(counts, 0, NGRP * 4, stream);
  // zero padded f rows so logits tiles touching them stay finite
  hipMemsetAsync(fS + (size_t)M_N * FDIM, 0, (size_t)(M_PAD - M_N) * FDIM * 2, stream);
  hipMemsetAsync(fT + (size_t)M_N * FDIM, 0, (size_t)(M_PAD - M_N) * FDIM * 2, stream);

  castw_kernel<<<dim3((CIN*CIN + 255) / 256, 4), 256, 0, stream>>>(
      sW1, w1bS, tW1, w1bT, sW2, w2bS, tW2, w2bT);
  build_lists_kernel<<<dim3((M_N + 63) / 64), 64, 0, stream>>>(sb, si, counts, lists);

  stats_kernel<<<dim3(256, 2), 512, 0, stream>>>(xS, xT, w1bS, w1bT, stats,
                                                 counts, lists, xsS, xsT);
  conv1_kernel<<<dim3(247, 2, 2), 256, 0, stream>>>(xsS, xsT, w1bS, w1bT, stats,
                                                    sGamma, sBeta, tGamma, tBeta, hrS, hrT);
  conv2_kernel<<<dim3(247, 2), 256, 0, stream>>>(hrS, hrT, w2bS, w2bT, sB2, tB2, fS, fT);

  if (haveLT){
    logits_kernel<<<dim3(62, 62), 256, 0, stream>>>(fS, fT, L, LT);
    loss_kernel<<<dim3(M_N), 256, 0, stream>>>(L, labels, out);
    loss_kernel<<<dim3(M_N), 256, 0, stream>>>(LT, labels, out);
  } else {
    logits_kernel<<<dim3(62, 62), 256, 0, stream>>>(fS, fT, L, nullptr);
    loss_kernel<<<dim3(M_N), 256, 0, stream>>>(L, labels, out);
    logits_kernel<<<dim3(62, 62), 256, 0, stream>>>(fT, fS, L, nullptr);
    loss_kernel<<<dim3(M_N), 256, 0, stream>>>(L, labels, out);
  }
}

// Round 13
// 600.343 us; speedup vs baseline: 2.2060x; 1.0342x over previous
//
#include <hip/hip_runtime.h>
#include <hip/hip_bf16.h>

#define A_N 152
#define V_N 26
#define M_N 3952          // A_N*V_N, = 247*16 exactly
#define M_PAD 3968        // 62*64
#define CIN 512
#define FDIM 256
#define HW_SZ 16384
#define P_TOT 131072.0f   // 8*16384
#define TEMP_INV 14.285714285714286f
#define NGRP 2048         // 8 images * 256 groups of 64 px
#define LCAP 64           // max samples per pixel-group

typedef __attribute__((ext_vector_type(8))) short bf16x8;
typedef __attribute__((ext_vector_type(4))) float f32x4;

static __device__ __forceinline__ short f2bf(float x){
  union { float f; unsigned u; } v; v.f = x;
  unsigned r = (v.u + 0x7FFFu + ((v.u >> 16) & 1u)) >> 16;
  return (short)r;
}

// Load an MFMA 16x16x32 A/B fragment from a row-major [rows][ld] bf16 matrix.
static __device__ __forceinline__ bf16x8 ldfrag(const short* __restrict__ base, int ld,
                                                int row, int k, int lane){
  return *(const bf16x8*)(base + (size_t)(row + (lane & 15)) * ld + k + ((lane >> 4) << 3));
}

// Fragment-packed load: frag (dtile, ktile) is 64 lanes x 16B CONTIGUOUS (1KB).
// packed[((dtile*16+ktile)*64+lane)*8+j] == W[(dtile*16+(lane&15))*CIN + ktile*32 + (lane>>4)*8 + j]
static __device__ __forceinline__ bf16x8 ldfragP(const short* __restrict__ base,
                                                 int dtile, int ktile, int lane){
  return *(const bf16x8*)(base + ((((size_t)dtile << 4) + ktile) << 9) + (lane << 3));
}

// convert+store 4 px of channel tid into the XOR-swizzled [px][c] LDS tile.
// float4 BY VALUE (R1 lesson: address-taken float4 arrays go to scratch).
static __device__ __forceinline__ void cvt4(short* __restrict__ lds, float4 v,
                                            int px, int tid){
  lds[(px+0)*512 + (tid ^ (((px+0)&7)<<3))] = f2bf(v.x);
  lds[(px+1)*512 + (tid ^ (((px+1)&7)<<3))] = f2bf(v.y);
  lds[(px+2)*512 + (tid ^ (((px+2)&7)<<3))] = f2bf(v.z);
  lds[(px+3)*512 + (tid ^ (((px+3)&7)<<3))] = f2bf(v.w);
}

// ---------------------------------------------------------------- weights cast
// W1 (y=0,1): cast AND repack into MFMA-fragment order (see ldfragP).
// W2 (y=2,3): plain cast.
__global__ void castw_kernel(const float* __restrict__ a0, short* __restrict__ o0,
                             const float* __restrict__ a1, short* __restrict__ o1,
                             const float* __restrict__ a2, short* __restrict__ o2,
                             const float* __restrict__ a3, short* __restrict__ o3){
  const float* a; short* o; int n;
  switch (blockIdx.y){
    case 0: a = a0; o = o0; n = CIN*CIN; break;
    case 1: a = a1; o = o1; n = CIN*CIN; break;
    case 2: a = a2; o = o2; n = FDIM*CIN; break;
    default: a = a3; o = o3; n = FDIM*CIN; break;
  }
  int i = blockIdx.x * 256 + threadIdx.x;
  if (i >= n) return;
  if (blockIdx.y < 2){
    int j  = i & 7;
    int ln = (i >> 3) & 63;
    int kt = (i >> 9) & 15;
    int dt = i >> 13;
    int row = dt * 16 + (ln & 15);
    int col = kt * 32 + ((ln >> 4) << 3) + j;
    o[i] = f2bf(a[row * CIN + col]);
  } else {
    o[i] = f2bf(a[i]);
  }
}

// ---------------------------------------------------------------- sample -> pixel-group lists
// Entry packs (px<<16)|m so the stats gather needs no dependent si load.
__global__ __launch_bounds__(64) void build_lists_kernel(
    const int* __restrict__ sb, const int* __restrict__ si,
    int* __restrict__ counts, int* __restrict__ lists){
  int m = blockIdx.x * 64 + threadIdx.x;
  if (m >= M_N) return;
  int a = m % A_N, v = m / A_N;
  int pix = si[a * V_N + v];
  int g = sb[a] * 256 + (pix >> 6);
  int slot = atomicAdd(&counts[g], 1);
  if (slot < LCAP) lists[g * LCAP + slot] = m | ((pix & 63) << 16);
}

// ---------------------------------------------------------------- BN statistics (+ fused gather)
// sums[d] = sum_p h, sums[512+d] = sum_p h^2, h = W1 . x (b1 cancels in BN).
// Base = R11 (128-px tiles, 128KB LDS, grid (256,2), 4 tiles/block, packed W1).
// R12 changes:
//  (a) bfr REGISTER DOUBLE-BUFFER with the PACKED layout (R2 structure + R10
//      layout, never tested together). Evidence: diag_mfma at idle L2 = 23%
//      MfmaUtil vs stats 14% -> loaded-L2 latency on the 4 bfr loads is the
//      residual suspect; packed frags are 4 contiguous 1KB loads whose latency
//      can hide under 32 MFMAs + 8 LDS reads when prefetched one kt ahead.
//  (b) gather moved AFTER the MFMA loop: its serial LDS reads + scattered xs
//      writes leave the staging->MFMA critical path and overlap the barrier.
__global__ __launch_bounds__(512, 2) void stats_kernel(
    const float* __restrict__ xS, const float* __restrict__ xT,
    const short* __restrict__ w1S, const short* __restrict__ w1T,
    float* __restrict__ stats,
    const int* __restrict__ counts, const int* __restrict__ lists,
    short* __restrict__ xsS, short* __restrict__ xsT){
  __shared__ short lds[128 * 512];       // 128 px x 512 c, c XOR-swizzled by ((px&7)<<3)
  const int t = blockIdx.y;
  const float* __restrict__ x = t ? xT : xS;
  const short* __restrict__ w1 = t ? w1T : w1S;
  float* sums = stats + t * 1024;
  short* __restrict__ xs = t ? xsT : xsS;

  const int tid  = threadIdx.x;
  const int lane = tid & 63;
  const int wave = tid >> 6;

  float rs[4] = {0.f,0.f,0.f,0.f};
  float rq[4] = {0.f,0.f,0.f,0.f};

  for (int it = 0; it < 4; ++it){
    const int T   = blockIdx.x + it * 256;   // 0..1023 tiles of 128 px
    const int n   = T >> 7;
    const int hw0 = (T & 127) << 7;
    const float* src = x + ((size_t)(n * CIN + tid)) * HW_SZ + hw0;  // c = tid

    const int g0 = T * 2, g1 = g0 + 1;       // the tile's two 64-px sample groups
    int cnt0 = counts[g0]; if (cnt0 > LCAP) cnt0 = LCAP;
    int cnt1 = counts[g1]; if (cnt1 > LCAP) cnt1 = LCAP;

    // stage 128 px x 512 c as bf16 in 8 chunks of 16 px (4 loads in flight/group)
    #pragma unroll
    for (int ch = 0; ch < 8; ++ch){
      float4 v0 = *(const float4*)(src + ch * 16 +  0);
      float4 v1 = *(const float4*)(src + ch * 16 +  4);
      float4 v2 = *(const float4*)(src + ch * 16 +  8);
      float4 v3 = *(const float4*)(src + ch * 16 + 12);
      cvt4(lds, v0, ch * 16 +  0, tid);
      cvt4(lds, v1, ch * 16 +  4, tid);
      cvt4(lds, v2, ch * 16 +  8, tid);
      cvt4(lds, v3, ch * 16 + 12, tid);
    }
    __syncthreads();

    f32x4 acc[8][4] = {};                  // [px-tile][d-tile]
    {
      // bfr double-buffer: prefetch kt+1's 4 packed frags before kt's MFMAs
      bf16x8 c0 = ldfragP(w1, wave*4 + 0, 0, lane);
      bf16x8 c1 = ldfragP(w1, wave*4 + 1, 0, lane);
      bf16x8 c2 = ldfragP(w1, wave*4 + 2, 0, lane);
      bf16x8 c3 = ldfragP(w1, wave*4 + 3, 0, lane);
      for (int kt = 0; kt < 16; ++kt){
        const int kn = (kt + 1) & 15;      // last-iter dummy reload (L2-hot, packed)
        bf16x8 n0 = ldfragP(w1, wave*4 + 0, kn, lane);
        bf16x8 n1 = ldfragP(w1, wave*4 + 1, kn, lane);
        bf16x8 n2 = ldfragP(w1, wave*4 + 2, kn, lane);
        bf16x8 n3 = ldfragP(w1, wave*4 + 3, kn, lane);
        const int kk = kt << 5;
        #pragma unroll
        for (int pi = 0; pi < 8; ++pi){
          int px = pi*16 + (lane & 15);
          int c  = (kk + ((lane >> 4) << 3)) ^ ((px & 7) << 3);
          bf16x8 af = *(const bf16x8*)(lds + px*512 + c);
          acc[pi][0] = __builtin_amdgcn_mfma_f32_16x16x32_bf16(af, c0, acc[pi][0], 0, 0, 0);
          acc[pi][1] = __builtin_amdgcn_mfma_f32_16x16x32_bf16(af, c1, acc[pi][1], 0, 0, 0);
          acc[pi][2] = __builtin_amdgcn_mfma_f32_16x16x32_bf16(af, c2, acc[pi][2], 0, 0, 0);
          acc[pi][3] = __builtin_amdgcn_mfma_f32_16x16x32_bf16(af, c3, acc[pi][3], 0, 0, 0);
        }
        c0 = n0; c1 = n1; c2 = n2; c3 = n3;
      }
    }
    #pragma unroll
    for (int di = 0; di < 4; ++di){
      float s = 0.f, q2 = 0.f;
      #pragma unroll
      for (int pi = 0; pi < 8; ++pi)
        #pragma unroll
        for (int r = 0; r < 4; ++r){ float vv = acc[pi][di][r]; s += vv; q2 += vv*vv; }
      rs[di] += s; rq[di] += q2;
    }

    // fused gather AFTER MFMA: off the staging->MFMA critical path; xs writes
    // overlap the closing barrier / next tile's staging. LDS still valid here.
    for (int s = 0; s < cnt0; ++s){
      int e = lists[g0 * LCAP + s];
      int m = e & 0xFFFF, px = e >> 16;
      xs[(size_t)m * CIN + tid] = lds[px * 512 + (tid ^ ((px & 7) << 3))];
    }
    for (int s = 0; s < cnt1; ++s){
      int e = lists[g1 * LCAP + s];
      int m = e & 0xFFFF, px = (e >> 16) + 64;
      xs[(size_t)m * CIN + tid] = lds[px * 512 + (tid ^ ((px & 7) << 3))];
    }
    __syncthreads();
  }
  #pragma unroll
  for (int di = 0; di < 4; ++di){
    float s = rs[di], q2 = rq[di];
    s  += __shfl_xor(s, 16, 64);  s  += __shfl_xor(s, 32, 64);
    q2 += __shfl_xor(q2, 16, 64); q2 += __shfl_xor(q2, 32, 64);
    if ((lane & 48) == 0){
      int d = wave * 64 + di*16 + lane;
      atomicAdd(&sums[d], s);
      atomicAdd(&sums[512 + d], q2);
    }
  }
}

// ---------------------------------------------------------------- conv1 + BN + ReLU at samples
// w1 is fragment-packed (same tile-16 geometry as stats) -> ldfragP.
__global__ __launch_bounds__(256) void conv1_kernel(
    const short* __restrict__ xsS, const short* __restrict__ xsT,
    const short* __restrict__ w1S, const short* __restrict__ w1T,
    const float* __restrict__ stats,
    const float* __restrict__ gS, const float* __restrict__ bS,
    const float* __restrict__ gT, const float* __restrict__ bT,
    short* __restrict__ hrS, short* __restrict__ hrT){
  const int t = blockIdx.z;
  const short* xs = t ? xsT : xsS;
  const short* w1 = t ? w1T : w1S;
  const float* sums  = stats + t * 1024;
  const float* gamma = t ? gT : gS;
  const float* beta  = t ? bT : bS;
  short* hr = t ? hrT : hrS;

  const int lane = threadIdx.x & 63;
  const int wave = threadIdx.x >> 6;
  const int m0 = blockIdx.x * 16;
  const int dt0 = (blockIdx.y * 4 + wave) * 4;      // dtile base
  const int d0  = dt0 * 16;

  f32x4 acc[4] = {};
  for (int kk = 0; kk < CIN; kk += 32){
    bf16x8 a = ldfrag(xs, CIN, m0, kk, lane);
    #pragma unroll
    for (int di = 0; di < 4; ++di){
      bf16x8 b = ldfragP(w1, dt0 + di, kk >> 5, lane);
      acc[di] = __builtin_amdgcn_mfma_f32_16x16x32_bf16(a, b, acc[di], 0, 0, 0);
    }
  }
  const float invP = 1.f / P_TOT;
  #pragma unroll
  for (int di = 0; di < 4; ++di){
    int d = d0 + di*16 + (lane & 15);
    float mu  = sums[d] * invP;
    float var = sums[512 + d] * invP - mu * mu;
    float sc  = gamma[d] * rsqrtf(var + 1e-5f);
    float sh  = beta[d] - mu * sc;
    #pragma unroll
    for (int r = 0; r < 4; ++r){
      int m = m0 + ((lane >> 4) << 2) + r;
      float v = fmaxf(acc[di][r] * sc + sh, 0.f);
      hr[(size_t)m * CIN + d] = f2bf(v);
    }
  }
}

// ---------------------------------------------------------------- conv2 + bias + L2 normalize
__global__ __launch_bounds__(256) void conv2_kernel(
    const short* __restrict__ hrS, const short* __restrict__ hrT,
    const short* __restrict__ w2S, const short* __restrict__ w2T,
    const float* __restrict__ b2S, const float* __restrict__ b2T,
    short* __restrict__ fS, short* __restrict__ fT){
  __shared__ float ssum[4][16];
  const int t = blockIdx.y;
  const short* hr = t ? hrT : hrS;
  const short* w2 = t ? w2T : w2S;
  const float* b2 = t ? b2T : b2S;
  short* f = t ? fT : fS;

  const int lane = threadIdx.x & 63;
  const int wave = threadIdx.x >> 6;
  const int m0 = blockIdx.x * 16;
  const int e0 = wave * 64;

  f32x4 acc[4] = {};
  for (int kk = 0; kk < CIN; kk += 32){
    bf16x8 a = ldfrag(hr, CIN, m0, kk, lane);
    #pragma unroll
    for (int ei = 0; ei < 4; ++ei){
      bf16x8 b = ldfrag(w2, CIN, e0 + ei*16, kk, lane);
      acc[ei] = __builtin_amdgcn_mfma_f32_16x16x32_bf16(a, b, acc[ei], 0, 0, 0);
    }
  }
  float z[4][4];
  float part[4] = {0.f,0.f,0.f,0.f};
  #pragma unroll
  for (int ei = 0; ei < 4; ++ei){
    int e = e0 + ei*16 + (lane & 15);
    float bb = b2[e];
    #pragma unroll
    for (int r = 0; r < 4; ++r){
      float v = acc[ei][r] + bb;
      z[ei][r] = v;
      part[r] += v * v;
    }
  }
  #pragma unroll
  for (int r = 0; r < 4; ++r){
    float p = part[r];
    p += __shfl_xor(p, 1, 64); p += __shfl_xor(p, 2, 64);
    p += __shfl_xor(p, 4, 64); p += __shfl_xor(p, 8, 64);
    part[r] = p;
  }
  if ((lane & 15) == 0){
    #pragma unroll
    for (int r = 0; r < 4; ++r) ssum[wave][((lane >> 4) << 2) + r] = part[r];
  }
  __syncthreads();
  #pragma unroll
  for (int r = 0; r < 4; ++r){
    int mrow = ((lane >> 4) << 2) + r;
    float tot = ssum[0][mrow] + ssum[1][mrow] + ssum[2][mrow] + ssum[3][mrow];
    float sc = 1.f / fmaxf(sqrtf(tot), 1e-12f);
    #pragma unroll
    for (int ei = 0; ei < 4; ++ei){
      int e = e0 + ei*16 + (lane & 15);
      f[(size_t)(m0 + mrow) * FDIM + e] = f2bf(z[ei][r] * sc);
    }
  }
}

// ---------------------------------------------------------------- logits = fa . fb^T / TEMP
// 4-wave blocks computing 64x64 tiles (grid 62x62). LT = logits^T written via a
// 64x65-padded LDS tile with coalesced 64B row-chunks (logits(fT,fS) ==
// logits(fS,fT)^T exactly, so the second logits dispatch is redundant). L is
// M_PAD rows (padded fa rows are zero -> rows 3952+ are zeros, never read).
__global__ __launch_bounds__(256) void logits_kernel(
    const short* __restrict__ fa, const short* __restrict__ fb,
    float* __restrict__ L, float* __restrict__ LT){
  __shared__ float trl[64 * 65];
  const int tid  = threadIdx.x;
  const int lane = tid & 63;
  const int wave = tid >> 6;
  const int m0 = blockIdx.x * 64;
  const int n0 = blockIdx.y * 64;
  f32x4 acc[4] = {};
  for (int kk = 0; kk < FDIM; kk += 32){
    bf16x8 a = ldfrag(fa, FDIM, m0 + wave * 16, kk, lane);
    #pragma unroll
    for (int ni = 0; ni < 4; ++ni){
      bf16x8 b = ldfrag(fb, FDIM, n0 + ni*16, kk, lane);
      acc[ni] = __builtin_amdgcn_mfma_f32_16x16x32_bf16(a, b, acc[ni], 0, 0, 0);
    }
  }
  #pragma unroll
  for (int ni = 0; ni < 4; ++ni){
    int colL = ni*16 + (lane & 15);
    #pragma unroll
    for (int r = 0; r < 4; ++r){
      int rowL = wave*16 + ((lane >> 4) << 2) + r;
      float val = acc[ni][r] * TEMP_INV;
      L[(size_t)(m0 + rowL) * M_PAD + (n0 + colL)] = val;
      trl[colL * 65 + rowL] = val;
    }
  }
  if (LT){
    __syncthreads();
    const int rj = tid >> 2;            // 0..63: n-row within tile
    const int cq = (tid & 3) << 4;      // 0,16,32,48: m-col quad base
    float* dst = LT + (size_t)(n0 + rj) * M_PAD + m0 + cq;
    #pragma unroll
    for (int q = 0; q < 4; ++q){
      f32x4 tmp;
      tmp.x = trl[rj*65 + cq + q*4 + 0];
      tmp.y = trl[rj*65 + cq + q*4 + 1];
      tmp.z = trl[rj*65 + cq + q*4 + 2];
      tmp.w = trl[rj*65 + cq + q*4 + 3];
      *(f32x4*)(dst + q*4) = tmp;
    }
  }
}

// ---------------------------------------------------------------- per-row contrastive reduction
// grid (M_N, 2): y selects L (S->T direction) or LT (T->S) — one launch for both.
// Fallback path launches with grid (M_N, 1) and LT == L.
__global__ __launch_bounds__(256) void loss_kernel(
    const float* __restrict__ L, const float* __restrict__ LT,
    const int* __restrict__ labels, float* __restrict__ out){
  __shared__ float row[M_N];
  __shared__ float red[4];
  const int m1 = blockIdx.x;
  const int tid = threadIdx.x;
  const int lab1 = labels[m1 % A_N];
  const float* Lr = (blockIdx.y ? LT : L) + (size_t)m1 * M_PAD;

  float mx = -3.4e38f;
  for (int j = tid; j < M_N; j += 256){ float v = Lr[j]; row[j] = v; mx = fmaxf(mx, v); }
  #pragma unroll
  for (int s = 1; s < 64; s <<= 1) mx = fmaxf(mx, __shfl_xor(mx, s, 64));
  if ((tid & 63) == 0) red[tid >> 6] = mx;
  __syncthreads();
  mx = fmaxf(fmaxf(red[0], red[1]), fmaxf(red[2], red[3]));
  __syncthreads();

  float negp = 0.f;
  for (int j = tid; j < M_N; j += 256){
    int labj = labels[j % A_N];
    float e = __expf(row[j] - mx);
    negp += (labj != lab1) ? e : 0.f;
  }
  #pragma unroll
  for (int s = 1; s < 64; s <<= 1) negp += __shfl_xor(negp, s, 64);
  if ((tid & 63) == 0) red[tid >> 6] = negp;
  __syncthreads();
  float neg = red[0] + red[1] + red[2] + red[3];
  __syncthreads();

  float ps = 0.f, pc = 0.f;
  for (int j = tid; j < M_N; j += 256){
    int labj = labels[j % A_N];
    if (labj == lab1 && j != m1){
      float l = row[j] - mx;
      ps += l - __logf(__expf(l) + neg);
      pc += 1.f;
    }
  }
  #pragma unroll
  for (int s = 1; s < 64; s <<= 1) ps += __shfl_xor(ps, s, 64);
  #pragma unroll
  for (int s = 1; s < 64; s <<= 1) pc += __shfl_xor(pc, s, 64);
  if ((tid & 63) == 0) red[tid >> 6] = ps;
  __syncthreads();
  ps = red[0] + red[1] + red[2] + red[3];
  __syncthreads();
  if ((tid & 63) == 0) red[tid >> 6] = pc;
  __syncthreads();
  if (tid == 0){
    pc = red[0] + red[1] + red[2] + red[3];
    float mlpp = ps / (pc + 1e-6f);
    atomicAdd(out, -0.5f / (float)M_N * mlpp);
  }
}

// ---------------------------------------------------------------- host launch
extern "C" void kernel_launch(void* const* d_in, const int* in_sizes, int n_in,
                              void* d_out, int out_size, void* d_ws, size_t ws_size,
                              hipStream_t stream){
  const float* xS     = (const float*)d_in[0];
  const float* xT     = (const float*)d_in[1];
  const int*   sb     = (const int*)d_in[2];
  const int*   si     = (const int*)d_in[3];
  const int*   labels = (const int*)d_in[4];
  const float* sW1    = (const float*)d_in[5];
  const float* sGamma = (const float*)d_in[7];
  const float* sBeta  = (const float*)d_in[8];
  const float* sW2    = (const float*)d_in[9];
  const float* sB2    = (const float*)d_in[10];
  const float* tW1    = (const float*)d_in[11];
  const float* tGamma = (const float*)d_in[13];
  const float* tBeta  = (const float*)d_in[14];
  const float* tW2    = (const float*)d_in[15];
  const float* tB2    = (const float*)d_in[16];
  float* out = (float*)d_out;

  char* ws = (char*)d_ws;
  size_t off = 0;
  auto alloc = [&](size_t bytes) -> void* {
    void* p = ws + off;
    off = (off + bytes + 255) & ~(size_t)255;
    return p;
  };
  short* w1bS = (short*)alloc((size_t)CIN * CIN * 2);
  short* w1bT = (short*)alloc((size_t)CIN * CIN * 2);
  short* w2bS = (short*)alloc((size_t)FDIM * CIN * 2);
  short* w2bT = (short*)alloc((size_t)FDIM * CIN * 2);
  float* stats = (float*)alloc(2 * 1024 * 4);
  int* counts = (int*)alloc(NGRP * 4);
  int* lists  = (int*)alloc((size_t)NGRP * LCAP * 4);
  short* xsS = (short*)alloc((size_t)M_N * CIN * 2);
  short* xsT = (short*)alloc((size_t)M_N * CIN * 2);
  short* hrS = (short*)alloc((size_t)M_N * CIN * 2);
  short* hrT = (short*)alloc((size_t)M_N * CIN * 2);
  short* fS  = (short*)alloc((size_t)M_PAD * FDIM * 2);
  short* fT  = (short*)alloc((size_t)M_PAD * FDIM * 2);
  float* L   = (float*)alloc((size_t)M_PAD * M_PAD * 4);
  float* LT  = (float*)alloc((size_t)M_PAD * M_PAD * 4);
  const bool haveLT = (off <= ws_size);   // fall back to two logits passes if tight

  (void)hipMemsetAsync(d_out, 0, sizeof(float), stream);
  (void)hipMemsetAsync(stats, 0, 2 * 1024 * 4, stream);
  (void)hipMemsetAsync(counts, 0, NGRP * 4, stream);
  // zero padded f rows so logits tiles touching them stay finite
  (void)hipMemsetAsync(fS + (size_t)M_N * FDIM, 0, (size_t)(M_PAD - M_N) * FDIM * 2, stream);
  (void)hipMemsetAsync(fT + (size_t)M_N * FDIM, 0, (size_t)(M_PAD - M_N) * FDIM * 2, stream);

  castw_kernel<<<dim3((CIN*CIN + 255) / 256, 4), 256, 0, stream>>>(
      sW1, w1bS, tW1, w1bT, sW2, w2bS, tW2, w2bT);
  build_lists_kernel<<<dim3((M_N + 63) / 64), 64, 0, stream>>>(sb, si, counts, lists);

  stats_kernel<<<dim3(256, 2), 512, 0, stream>>>(xS, xT, w1bS, w1bT, stats,
                                                 counts, lists, xsS, xsT);
  conv1_kernel<<<dim3(247, 2, 2), 256, 0, stream>>>(xsS, xsT, w1bS, w1bT, stats,
                                                    sGamma, sBeta, tGamma, tBeta, hrS, hrT);
  conv2_kernel<<<dim3(247, 2), 256, 0, stream>>>(hrS, hrT, w2bS, w2bT, sB2, tB2, fS, fT);

  if (haveLT){
    logits_kernel<<<dim3(62, 62), 256, 0, stream>>>(fS, fT, L, LT);
    loss_kernel<<<dim3(M_N, 2), 256, 0, stream>>>(L, LT, labels, out);
  } else {
    logits_kernel<<<dim3(62, 62), 256, 0, stream>>>(fS, fT, L, nullptr);
    loss_kernel<<<dim3(M_N, 1), 256, 0, stream>>>(L, L, labels, out);
    logits_kernel<<<dim3(62, 62), 256, 0, stream>>>(fT, fS, L, nullptr);
    loss_kernel<<<dim3(M_N, 1), 256, 0, stream>>>(L, L, labels, out);
  }
}